// Round 5
// baseline (15971.892 us; speedup 1.0000x reference)
//
#include <hip/hip_runtime.h>

typedef unsigned short u16;
typedef unsigned int u32;

#define NN 10000
#define EE 200000

#define DEVI __device__ __forceinline__

DEVI float us2f(u16 u) {
    union { u32 i; float f; } v; v.i = ((u32)u) << 16; return v.f;
}
DEVI u16 f2bu(float f) {
    union { float f; u32 i; } v; v.f = f;
    u32 x = v.i;
    u32 r = (x + 0x7fffu + ((x >> 16) & 1u)) >> 16;
    return (u16)r;
}
DEVI float siluf(float x) { return x / (1.f + __expf(-x)); }
DEVI float sigmf(float x) { return 1.f / (1.f + __expf(-x)); }
DEVI float waveSum(float v) {
#pragma unroll
    for (int o = 32; o > 0; o >>= 1) v += __shfl_xor(v, o);
    return v;
}

// dtype flag: 1 = float inputs are bf16, 0 = float inputs are f32
__device__ int g_bf;

DEVI float ldv(const void* p, size_t i, int bf) {
    return bf ? us2f(((const u16*)p)[i]) : ((const float*)p)[i];
}
DEVI u16 stg(const void* p, size_t i, int bf) {   // stage into bf16 LDS
    return bf ? ((const u16*)p)[i] : f2bu(((const float*)p)[i]);
}
DEVI void stv(void* p, size_t i, int bf, float v) {
    if (bf) ((u16*)p)[i] = f2bu(v); else ((float*)p)[i] = v;
}

// ---- scratch as module-owned device globals: zero bytes of d_ws used ----
__device__ float g_z[(size_t)EE * 64];   // 51.2 MB
__device__ float g_bball[4 * EE];        // 3.2 MB
__device__ float g_MT[4 * 4096];         // 64 KB
__device__ float g_msum[NN * 64];        // 2.56 MB
__device__ float g_xsum[NN * 3];
__device__ float g_nsum[NN * 3];
__device__ float g_cnt[NN];

// ---------------- K-2: detect dtype of float inputs ----------------
__global__ void k_detect(const void* __restrict__ h)
{
    if (threadIdx.x == 0) {
        const u16* p = (const u16*)h;
        int bf = 1;
        for (int i = 0; i < 64; i++) {
            float v = us2f(p[i]);
            if (!(fabsf(v) < 1000.f)) bf = 0;   // NaN/inf/huge -> f32 data
        }
        g_bf = bf;
    }
}

// ---------------- K-1: zero accumulators ----------------
__global__ __launch_bounds__(256) void k_zero()
{
    int t = blockIdx.x * 256 + threadIdx.x;
    int nt = gridDim.x * 256;
    for (int i = t; i < NN * 64; i += nt) g_msum[i] = 0.f;
    for (int i = t; i < NN * 3; i += nt) { g_xsum[i] = 0.f; g_nsum[i] = 0.f; }
    for (int i = t; i < NN; i += nt) g_cnt[i] = 0.f;
}

// ---------------- K0: MT[hd][j][i] = sum_d Wk[i][d] * Wq[j][d] ----------------
__global__ __launch_bounds__(256) void k_prep(
    const void* __restrict__ Wq, const void* __restrict__ Wk)
{
    int bf = g_bf;
    int t = blockIdx.x * 256 + threadIdx.x;      // [0, 16384)
    int hd = t >> 12;
    int rem = t & 4095;
    int j = rem >> 6;
    int i = rem & 63;
    size_t wkb = (size_t)hd * 4096 + i * 64;
    size_t wqb = (size_t)hd * 4096 + j * 64;
    float acc = 0.f;
    for (int d = 0; d < 64; d++) acc += ldv(Wk, wkb + d, bf) * ldv(Wq, wqb + d, bf);
    g_MT[hd * 4096 + j * 64 + i] = acc;
}

// ---------------- K1: fused edge kernel ----------------
__global__ __launch_bounds__(256) void k_edge(
    const void* __restrict__ h, const void* __restrict__ na, const void* __restrict__ ea,
    const void* __restrict__ coord, const void* __restrict__ nvecs,
    const int* __restrict__ edges,
    const void* __restrict__ chW1, const void* __restrict__ chb1,
    const void* __restrict__ chW2, const void* __restrict__ chb2,
    const void* __restrict__ pW1, const void* __restrict__ pb1,
    const void* __restrict__ pW2, const void* __restrict__ pb2,
    const void* __restrict__ shW, const void* __restrict__ shb,
    const void* __restrict__ attW, const void* __restrict__ attb,
    const void* __restrict__ Wb,
    const void* __restrict__ uW1, const void* __restrict__ ub1,
    const void* __restrict__ uW2, const void* __restrict__ ub2,
    const void* __restrict__ xW1, const void* __restrict__ xb1,
    const void* __restrict__ xW2, const void* __restrict__ xb2,
    const void* __restrict__ nW1, const void* __restrict__ nb1,
    const void* __restrict__ nW2, const void* __restrict__ nb2,
    int E)
{
    __shared__ u16 sW1[272 * 64];
    __shared__ u16 sW2[64 * 64];
    __shared__ u16 sSH[64 * 64];
    __shared__ u16 sPW2[64 * 64];
    __shared__ float sPW1[128], sATT[64];
    __shared__ float sCB1[64], sCB2[64], sPB1[64], sPB2[64], sSHB[64];
    __shared__ float sWB[256];
    __shared__ float sScal[4];
    int bf = g_bf;
    int tid = threadIdx.x;
    for (int i = tid; i < 272 * 64; i += 256) sW1[i] = stg(chW1, i, bf);
    for (int i = tid; i < 4096; i += 256) {
        sW2[i] = stg(chW2, i, bf); sSH[i] = stg(shW, i, bf); sPW2[i] = stg(pW2, i, bf);
    }
    if (tid < 128) sPW1[tid] = ldv(pW1, tid, bf);
    if (tid < 64) {
        sATT[tid] = ldv(attW, tid, bf);
        sCB1[tid] = ldv(chb1, tid, bf); sCB2[tid] = ldv(chb2, tid, bf);
        sPB1[tid] = ldv(pb1, tid, bf);  sPB2[tid] = ldv(pb2, tid, bf);
        sSHB[tid] = ldv(shb, tid, bf);
    }
    sWB[tid] = ldv(Wb, tid, bf);
    if (tid == 0) {
        sScal[0] = ldv(attb, 0, bf); sScal[1] = ldv(ub2, 0, bf);
        sScal[2] = ldv(xb2, 0, bf);  sScal[3] = ldv(nb2, 0, bf);
    }
    __syncthreads();
    int lane = tid & 63;
    int wid = blockIdx.x * 4 + (tid >> 6);
    int nw = gridDim.x * 4;
    for (int e = wid; e < E; e += nw) {
        int r = edges[e], c = edges[E + e];
        float dl = (lane < 3) ? (ldv(coord, r * 3 + lane, bf) - ldv(coord, c * 3 + lane, bf)) : 0.f;
        float radial = waveSum(dl * dl);
        float nvr = (lane < 3) ? ldv(nvecs, r * 3 + lane, bf) : 0.f;
        float nvc = (lane < 3) ? ldv(nvecs, c * 3 + lane, bf) : 0.f;
        float nprod = waveSum(nvr * nvc);
        float cdl = dl / (sqrtf(radial) + 1e-8f);
        // chem layer 1 (272 -> 64)
        float i0 = ldv(h, (size_t)r * 64 + lane, bf);
        float i1 = ldv(h, (size_t)c * 64 + lane, bf);
        float i2 = ldv(na, (size_t)r * 64 + lane, bf);
        float i3 = ldv(na, (size_t)c * 64 + lane, bf);
        float i4 = (lane < 16) ? ldv(ea, (size_t)e * 16 + lane, bf) : 0.f;
        float acc = sCB1[lane];
        for (int i = 0; i < 64; i++) acc += __shfl(i0, i) * us2f(sW1[i * 64 + lane]);
        for (int i = 0; i < 64; i++) acc += __shfl(i1, i) * us2f(sW1[(64 + i) * 64 + lane]);
        for (int i = 0; i < 64; i++) acc += __shfl(i2, i) * us2f(sW1[(128 + i) * 64 + lane]);
        for (int i = 0; i < 64; i++) acc += __shfl(i3, i) * us2f(sW1[(192 + i) * 64 + lane]);
        for (int i = 0; i < 16; i++) acc += __shfl(i4, i) * us2f(sW1[(256 + i) * 64 + lane]);
        float t1 = siluf(acc);
        float a2 = sCB2[lane];
        for (int i = 0; i < 64; i++) a2 += __shfl(t1, i) * us2f(sW2[i * 64 + lane]);
        float chem = siluf(a2);
        // pos MLP
        float p1 = siluf(sPB1[lane] + nprod * sPW1[lane] + radial * sPW1[64 + lane]);
        float ap = sPB2[lane];
        for (int i = 0; i < 64; i++) ap += __shfl(p1, i) * us2f(sPW2[i * 64 + lane]);
        float pos = siluf(ap);
        // sh -> out -> z
        float a3 = sSHB[lane];
        for (int i = 0; i < 64; i++) a3 += __shfl(chem, i) * us2f(sSH[i * 64 + lane]);
        float outv = siluf(a3) * pos;
        float satt = waveSum(outv * sATT[lane]) + sScal[0];
        float zl = outv * sigmf(satt);
        g_z[(size_t)e * 64 + lane] = zl;
        // b for 4 heads
#pragma unroll
        for (int hd = 0; hd < 4; hd++) {
            float bv = waveSum(zl * sWB[hd * 64 + lane]);
            if (lane == 0) g_bball[hd * EE + e] = bv;
        }
        // phi_u (chem), phi_x / phi_n (pos)
        float au = ldv(ub1, lane, bf);
        for (int i = 0; i < 64; i++) au += __shfl(chem, i) * ldv(uW1, i * 64 + lane, bf);
        float phiu = waveSum(siluf(au) * ldv(uW2, lane, bf)) + sScal[1];
        float ax = ldv(xb1, lane, bf);
        float an = ldv(nb1, lane, bf);
        for (int i = 0; i < 64; i++) {
            float pi = __shfl(pos, i);
            ax += pi * ldv(xW1, i * 64 + lane, bf);
            an += pi * ldv(nW1, i * 64 + lane, bf);
        }
        float phix = waveSum(siluf(ax) * ldv(xW2, lane, bf)) + sScal[2];
        float phin = waveSum(siluf(an) * ldv(nW2, lane, bf)) + sScal[3];
        if (lane < 3) {
            atomicAdd(&g_xsum[r * 3 + lane], cdl * (phiu * phix));
            atomicAdd(&g_nsum[r * 3 + lane], nvc * (phiu * phin));
        }
        if (lane == 0) atomicAdd(&g_cnt[r], 1.f);
    }
}

// ---------------- K2: per-head attention; folds out_W slice; scatter msum ----------------
__global__ __launch_bounds__(256) void k_attn(
    const void* __restrict__ Wg, const void* __restrict__ bg,
    const void* __restrict__ Wv, const void* __restrict__ oW,
    const int* __restrict__ klist, const int* __restrict__ edges,
    int hd, int E)
{
    __shared__ float sMT[4096];
    __shared__ u16 sG[4096], sV[4096], sOW[4096];
    __shared__ float sbg[64];
    int bf = g_bf;
    int tid = threadIdx.x;
    size_t wb = (size_t)hd * 4096;
    for (int i = tid; i < 4096; i += 256) {
        sMT[i] = g_MT[wb + i];
        sG[i] = stg(Wg, wb + i, bf);
        sV[i] = stg(Wv, wb + i, bf);
        sOW[i] = stg(oW, wb + i, bf);
    }
    if (tid < 64) sbg[tid] = ldv(bg, (size_t)hd * 64 + tid, bf);
    __syncthreads();
    const float* bb = g_bball + hd * EE;
    int lane = tid & 63;
    int wid = blockIdx.x * 4 + (tid >> 6);
    int nw = gridDim.x * 4;
    for (int e = wid; e < E; e += nw) {
        float zl = g_z[(size_t)e * 64 + lane];
        float ga = sbg[lane];
        float qp = 0.f;                  // q·k_ij = qp · z_ij
        for (int i = 0; i < 64; i++) {
            float zi = __shfl(zl, i);
            ga += zi * us2f(sG[i * 64 + lane]);
            qp += zi * sMT[i * 64 + lane];
        }
        float g = sigmf(ga);
        const int* kl = klist + (size_t)e * 32;
        float s[16], zj[16];
#pragma unroll
        for (int j = 0; j < 16; j++) {
            int ij = kl[j];
            float zij = 0.f, sj = 0.f;
            if (ij >= 0) {
                zij = g_z[(size_t)ij * 64 + lane];
                sj = 0.125f * waveSum(qp * zij) + bb[kl[16 + j]];
            }
            s[j] = sj; zj[j] = zij;
        }
        float mx = s[0];
#pragma unroll
        for (int j = 1; j < 16; j++) mx = fmaxf(mx, s[j]);
        float den = 0.f;
#pragma unroll
        for (int j = 0; j < 16; j++) { s[j] = __expf(s[j] - mx); den += s[j]; }
        float inv = 1.f / den;
        float zagg = 0.f;
#pragma unroll
        for (int j = 0; j < 16; j++) zagg += s[j] * zj[j];
        float o = 0.f;
        for (int i = 0; i < 64; i++) o += __shfl(zagg, i) * us2f(sV[i * 64 + lane]);
        float ho = g * o * inv;
        float acc = 0.f;
        for (int i = 0; i < 64; i++) acc += __shfl(ho, i) * us2f(sOW[i * 64 + lane]);
        atomicAdd(&g_msum[edges[e] * 64 + lane], acc);
    }
}

// ---------------- K3: node finalize -> h_new, coord_new, nv ----------------
__global__ __launch_bounds__(256) void k_node(
    const void* __restrict__ h, const void* __restrict__ na,
    const void* __restrict__ coord, const void* __restrict__ nvecs,
    const void* __restrict__ icoord, const void* __restrict__ invecs,
    const void* __restrict__ ob,
    const void* __restrict__ W1, const void* __restrict__ b1,
    const void* __restrict__ W2, const void* __restrict__ b2,
    void* __restrict__ out, int N)
{
    __shared__ u16 sW1[192 * 64], sW2[64 * 64];
    __shared__ float sb1[64], sb2[64];
    int bf = g_bf;
    int tid = threadIdx.x;
    for (int i = tid; i < 192 * 64; i += 256) sW1[i] = stg(W1, i, bf);
    for (int i = tid; i < 4096; i += 256) sW2[i] = stg(W2, i, bf);
    if (tid < 64) { sb1[tid] = ldv(b1, tid, bf); sb2[tid] = ldv(b2, tid, bf); }
    __syncthreads();
    size_t coff = (size_t)N * 64;            // coord_new starts here
    size_t noff = coff + (size_t)N * 3;      // nv starts here
    int lane = tid & 63;
    int wid = blockIdx.x * 4 + (tid >> 6);
    int nw = gridDim.x * 4;
    for (int n = wid; n < N; n += nw) {
        float craw = g_cnt[n];
        float cv = fmaxf(craw, 1.f);
        float rinv = 1.f / cv;
        float hl = ldv(h, (size_t)n * 64 + lane, bf);
        float al = ldv(na, (size_t)n * 64 + lane, bf);
        float obv = (craw > 0.f) ? ldv(ob, lane, bf) : 0.f;
        float ml = g_msum[n * 64 + lane] * rinv + obv;
        float acc = sb1[lane];
        for (int i = 0; i < 64; i++) acc += __shfl(hl, i) * us2f(sW1[i * 64 + lane]);
        for (int i = 0; i < 64; i++) acc += __shfl(al, i) * us2f(sW1[(64 + i) * 64 + lane]);
        for (int i = 0; i < 64; i++) acc += __shfl(ml, i) * us2f(sW1[(128 + i) * 64 + lane]);
        float t = siluf(acc);
        float a2 = sb2[lane];
        for (int i = 0; i < 64; i++) a2 += __shfl(t, i) * us2f(sW2[i * 64 + lane]);
        stv(out, (size_t)n * 64 + lane, bf, 0.2f * hl + 0.8f * a2);
        if (lane < 3) {
            float xa = g_xsum[n * 3 + lane] * rinv;
            stv(out, coff + n * 3 + lane, bf,
                0.2f * ldv(icoord, n * 3 + lane, bf) + 0.8f * ldv(coord, n * 3 + lane, bf) + xa);
        }
        float nl = (lane < 3)
            ? (0.2f * ldv(invecs, n * 3 + lane, bf) + 0.8f * ldv(nvecs, n * 3 + lane, bf)
               + g_nsum[n * 3 + lane] * rinv)
            : 0.f;
        float nn = sqrtf(waveSum(nl * nl)) + 1e-8f;
        if (lane < 3) stv(out, noff + n * 3 + lane, bf, nl / nn);
    }
}

extern "C" void kernel_launch(void* const* d_in, const int* in_sizes, int n_in,
                              void* d_out, int out_size, void* d_ws, size_t ws_size,
                              hipStream_t stream)
{
    const int N = in_sizes[0] / 64;      // 10000
    const int E = in_sizes[43] / 2;      // 200000
    const int* edges = (const int*)d_in[43];
    const int* klist = (const int*)d_in[44];

    k_detect<<<1, 64, 0, stream>>>(d_in[0]);
    k_zero<<<512, 256, 0, stream>>>();
    k_prep<<<64, 256, 0, stream>>>(d_in[19], d_in[20]);          // Wq, Wk
    k_edge<<<1024, 256, 0, stream>>>(
        d_in[0], d_in[4], d_in[3],            // h, node_attr, edge_attr
        d_in[1], d_in[2],                     // coord, nvecs
        edges,
        d_in[7], d_in[8], d_in[9], d_in[10],  // ch_W1, ch_b1, ch_W2, ch_b2
        d_in[11], d_in[12], d_in[13], d_in[14], // pos
        d_in[15], d_in[16],                   // sh_W, sh_b
        d_in[17], d_in[18],                   // att_W, att_b
        d_in[22],                             // Wb
        d_in[27], d_in[28], d_in[29], d_in[30], // phiu
        d_in[31], d_in[32], d_in[33], d_in[34], // phix
        d_in[35], d_in[36], d_in[37], d_in[38], // phin
        E);
    for (int hd = 0; hd < 4; ++hd) {
        k_attn<<<1024, 256, 0, stream>>>(
            d_in[23], d_in[24],               // Wg, bg
            d_in[21], d_in[25],               // Wv, out_W
            klist, edges, hd, E);
    }
    k_node<<<640, 256, 0, stream>>>(
        d_in[0], d_in[4],                     // h, node_attr
        d_in[1], d_in[2],                     // coord, nvecs
        d_in[5], d_in[6],                     // init_coord, init_nvecs
        d_in[26],                             // out_b
        d_in[39], d_in[40], d_in[41], d_in[42], // phih
        d_out, N);
}

// Round 6
// 2591.194 us; speedup vs baseline: 6.1639x; 6.1639x over previous
//
#include <hip/hip_runtime.h>

typedef unsigned short u16;
typedef unsigned int u32;
typedef __attribute__((ext_vector_type(8))) short s16x8;
typedef __attribute__((ext_vector_type(4))) float f32x4;

#define NN 10000
#define EE 200000
#define ES ((size_t)EE * 64)

#define DEVI __device__ __forceinline__

DEVI float us2f(u16 u) {
    union { u32 i; float f; } v; v.i = ((u32)u) << 16; return v.f;
}
DEVI u16 f2bu(float f) {
    union { float f; u32 i; } v; v.f = f;
    u32 x = v.i;
    return (u16)((x + 0x7fffu + ((x >> 16) & 1u)) >> 16);
}
DEVI float siluf(float x) { return x / (1.f + __expf(-x)); }
DEVI float sigmf(float x) { return 1.f / (1.f + __expf(-x)); }
DEVI float waveSum(float v) {
#pragma unroll
    for (int o = 32; o; o >>= 1) v += __shfl_xor(v, o);
    return v;
}
DEVI float quadSum(float v) {
#pragma unroll
    for (int o = 1; o < 16; o <<= 1) v += __shfl_xor(v, o);
    return v;
}

// ---- module-owned scratch (f32 data arrives in d_in; intermediates bf16 for MFMA) ----
__device__ u16 g_t1[ES];          // chem layer1 out
__device__ u16 g_chem[ES];
__device__ u16 g_p1[ES];          // pos layer1 out
__device__ u16 g_pos[ES];
__device__ u16 g_z16[ES];
__device__ u16 g_qp4[4][ES];      // per-head q-projected (reused as u after attn)
__device__ u16 g_g4[4][ES];       // per-head gate
__device__ u16 g_t4[4][ES];       // per-head aggregated z
__device__ u16 g_M[4 * 4096];     // Wq Wk^T per head, bf16, [hd][k][n]
__device__ float g_b[4 * (size_t)EE];
__device__ float g_phiu[EE], g_phix[EE], g_phin[EE];
__device__ float g_cdl[EE * 3];
__device__ float g_msum[NN * 64];
__device__ float g_xsum[NN * 3];
__device__ float g_nsum[NN * 3];
__device__ float g_cnt[NN];

// ---------------- zero accumulators ----------------
__global__ __launch_bounds__(256) void k_zero()
{
    int t = blockIdx.x * 256 + threadIdx.x;
    int nt = gridDim.x * 256;
    for (int i = t; i < NN * 64; i += nt) g_msum[i] = 0.f;
    for (int i = t; i < NN * 3; i += nt) { g_xsum[i] = 0.f; g_nsum[i] = 0.f; }
    for (int i = t; i < NN; i += nt) g_cnt[i] = 0.f;
}

// ---------------- M[hd][k][n] = sum_d Wq[hd][k][d] * Wk[hd][n][d] ----------------
__global__ __launch_bounds__(256) void k_prep(const float* __restrict__ Wq, const float* __restrict__ Wk)
{
    int t = blockIdx.x * 256 + threadIdx.x;          // [0, 16384)
    int hd = t >> 12, rem = t & 4095, k = rem >> 6, n = rem & 63;
    const float* wq = Wq + (size_t)hd * 4096 + k * 64;
    const float* wk = Wk + (size_t)hd * 4096 + n * 64;
    float acc = 0.f;
    for (int d = 0; d < 64; d++) acc += wq[d] * wk[d];
    g_M[t] = f2bu(acc);
}

// ---------------- geometry + pos layer1 ----------------
__global__ __launch_bounds__(256) void k_geom(
    const float* __restrict__ coord, const float* __restrict__ nvecs,
    const int* __restrict__ edges, const float* __restrict__ pW1, const float* __restrict__ pb1)
{
    int lane = threadIdx.x & 63;
    int wid = blockIdx.x * 4 + (threadIdx.x >> 6);
    int nw = gridDim.x * 4;
    float w0 = pW1[lane], w1 = pW1[64 + lane], b0 = pb1[lane];
    for (int e = wid; e < EE; e += nw) {
        int r = edges[e], c = edges[EE + e];
        float dl = (lane < 3) ? (coord[r * 3 + lane] - coord[c * 3 + lane]) : 0.f;
        float radial = waveSum(dl * dl);
        float nvr = (lane < 3) ? nvecs[r * 3 + lane] : 0.f;
        float nvc = (lane < 3) ? nvecs[c * 3 + lane] : 0.f;
        float nprod = waveSum(nvr * nvc);
        if (lane < 3) g_cdl[e * 3 + lane] = dl / (sqrtf(radial) + 1e-8f);
        g_p1[(size_t)e * 64 + lane] = f2bu(siluf(b0 + nprod * w0 + radial * w1));
    }
}

// ---------------- chem layer1: gathered-A GEMM, K=288 (272 + pad) ----------------
__global__ __launch_bounds__(256) void k_chem1(
    const float* __restrict__ h, const float* __restrict__ na, const float* __restrict__ ea,
    const int* __restrict__ edges, const float* __restrict__ W1, const float* __restrict__ b1)
{
    __shared__ u16 sBT[64 * 296];
    int tid = threadIdx.x;
    for (int i = tid; i < 64 * 296; i += 256) {
        int n = i / 296, k = i - n * 296;
        sBT[i] = (k < 272) ? f2bu(W1[k * 64 + n]) : (u16)0;
    }
    __syncthreads();
    int lane = tid & 63, q = lane >> 4, ln = lane & 15, w = tid >> 6;
    int m0 = blockIdx.x * 64 + w * 16;
    int e = m0 + ln;
    int r_ = edges[e], c_ = edges[EE + e];
    f32x4 acc[4];
#pragma unroll
    for (int t = 0; t < 4; t++) acc[t] = (f32x4){0.f, 0.f, 0.f, 0.f};
#pragma unroll
    for (int k0 = 0; k0 < 9; k0++) {
        int k = k0 * 32 + q * 8;
        s16x8 af = {0, 0, 0, 0, 0, 0, 0, 0};
        const float* p = nullptr;
        if (k < 64)       p = h  + (size_t)r_ * 64 + k;
        else if (k < 128) p = h  + (size_t)c_ * 64 + (k - 64);
        else if (k < 192) p = na + (size_t)r_ * 64 + (k - 128);
        else if (k < 256) p = na + (size_t)c_ * 64 + (k - 192);
        else if (k < 272) p = ea + (size_t)e * 16 + (k - 256);
        if (p) {
            float4 f0 = *(const float4*)(p);
            float4 f1 = *(const float4*)(p + 4);
            af[0] = (short)f2bu(f0.x); af[1] = (short)f2bu(f0.y);
            af[2] = (short)f2bu(f0.z); af[3] = (short)f2bu(f0.w);
            af[4] = (short)f2bu(f1.x); af[5] = (short)f2bu(f1.y);
            af[6] = (short)f2bu(f1.z); af[7] = (short)f2bu(f1.w);
        }
#pragma unroll
        for (int t = 0; t < 4; t++) {
            s16x8 bf = *(const s16x8*)(&sBT[(t * 16 + ln) * 296 + k0 * 32 + q * 8]);
            acc[t] = __builtin_amdgcn_mfma_f32_16x16x32_bf16(af, bf, acc[t], 0, 0, 0);
        }
    }
#pragma unroll
    for (int t = 0; t < 4; t++) {
        float bv = b1[t * 16 + ln];
#pragma unroll
        for (int r = 0; r < 4; r++)
            g_t1[(size_t)(m0 + q * 4 + r) * 64 + t * 16 + ln] = f2bu(siluf(acc[t][r] + bv));
    }
}

// ---------------- generic K=64, N=64 GEMM with fused epilogues ----------------
#define M_SILU 0
#define M_SIGM 1
#define M_PLAIN 2
#define M_MULT 3
#define M_ZEP 4
#define M_DOT 5
#define M_SCAT 6

template<int MODE>
__global__ __launch_bounds__(256) void k_gemm(
    const u16* __restrict__ A, const void* __restrict__ Bv,
    const float* __restrict__ bias,
    const void* __restrict__ aux,        // ZEP: pos(u16); MULT: mult(u16); DOT: w2(f32)
    const float* __restrict__ aux2,      // ZEP: attW; DOT: b2
    const float* __restrict__ aux3,      // ZEP: attb
    const float* __restrict__ aux4,      // ZEP: Wb[4][64]
    const int* __restrict__ edges0,      // SCAT
    u16* __restrict__ outb, float* __restrict__ outf)
{
    __shared__ u16 sBT[64 * 72];
    int tid = threadIdx.x;
    for (int i = tid; i < 4096; i += 256) {
        int k = i >> 6, n = i & 63;
        u16 wv = (MODE == M_PLAIN) ? ((const u16*)Bv)[i] : f2bu(((const float*)Bv)[i]);
        sBT[n * 72 + k] = wv;
    }
    __syncthreads();
    int lane = tid & 63, q = lane >> 4, ln = lane & 15, w = tid >> 6;
    int m0 = blockIdx.x * 64 + w * 16;
    f32x4 acc[4];
#pragma unroll
    for (int t = 0; t < 4; t++) acc[t] = (f32x4){0.f, 0.f, 0.f, 0.f};
    const u16* ar = A + (size_t)(m0 + ln) * 64;
#pragma unroll
    for (int k0 = 0; k0 < 2; k0++) {
        s16x8 af = *(const s16x8*)(ar + k0 * 32 + q * 8);
#pragma unroll
        for (int t = 0; t < 4; t++) {
            s16x8 bf = *(const s16x8*)(&sBT[(t * 16 + ln) * 72 + k0 * 32 + q * 8]);
            acc[t] = __builtin_amdgcn_mfma_f32_16x16x32_bf16(af, bf, acc[t], 0, 0, 0);
        }
    }
    int rows[4];
#pragma unroll
    for (int r = 0; r < 4; r++) rows[r] = m0 + q * 4 + r;
    float bv[4];
#pragma unroll
    for (int t = 0; t < 4; t++) bv[t] = bias ? bias[t * 16 + ln] : 0.f;

    if (MODE == M_SILU || MODE == M_SIGM || MODE == M_PLAIN || MODE == M_MULT) {
#pragma unroll
        for (int t = 0; t < 4; t++) {
#pragma unroll
            for (int r = 0; r < 4; r++) {
                float v = acc[t][r] + bv[t];
                if (MODE == M_SILU) v = siluf(v);
                if (MODE == M_SIGM) v = sigmf(v);
                if (MODE == M_MULT) v = v * us2f(((const u16*)aux)[(size_t)rows[r] * 64 + t * 16 + ln]);
                outb[(size_t)rows[r] * 64 + t * 16 + ln] = f2bu(v);
            }
        }
    } else if (MODE == M_ZEP) {
        float zv[4][4];
        float part[4] = {0.f, 0.f, 0.f, 0.f};
#pragma unroll
        for (int t = 0; t < 4; t++) {
            float aw = aux2[t * 16 + ln];
#pragma unroll
            for (int r = 0; r < 4; r++) {
                float o = siluf(acc[t][r] + bv[t]) * us2f(((const u16*)aux)[(size_t)rows[r] * 64 + t * 16 + ln]);
                zv[t][r] = o;
                part[r] += o * aw;
            }
        }
        float ab = aux3[0];
#pragma unroll
        for (int r = 0; r < 4; r++) {
            float sg = sigmf(quadSum(part[r]) + ab);
#pragma unroll
            for (int t = 0; t < 4; t++) {
                float z = zv[t][r] * sg;
                zv[t][r] = z;
                outb[(size_t)rows[r] * 64 + t * 16 + ln] = f2bu(z);
            }
        }
#pragma unroll
        for (int hd = 0; hd < 4; hd++) {
#pragma unroll
            for (int r = 0; r < 4; r++) {
                float p = 0.f;
#pragma unroll
                for (int t = 0; t < 4; t++) p += zv[t][r] * aux4[hd * 64 + t * 16 + ln];
                p = quadSum(p);
                if (ln == hd) outf[(size_t)hd * EE + rows[r]] = p;
            }
        }
    } else if (MODE == M_DOT) {
        float part[4] = {0.f, 0.f, 0.f, 0.f};
#pragma unroll
        for (int t = 0; t < 4; t++) {
            float w2 = ((const float*)aux)[t * 16 + ln];
#pragma unroll
            for (int r = 0; r < 4; r++) part[r] += siluf(acc[t][r] + bv[t]) * w2;
        }
        float b2 = aux2[0];
#pragma unroll
        for (int r = 0; r < 4; r++) {
            float s = quadSum(part[r]) + b2;
            if (ln == 0) outf[rows[r]] = s;
        }
    } else if (MODE == M_SCAT) {
#pragma unroll
        for (int r = 0; r < 4; r++) {
            int dst = edges0[rows[r]] * 64;
#pragma unroll
            for (int t = 0; t < 4; t++) atomicAdd(&outf[dst + t * 16 + ln], acc[t][r]);
        }
    }
}

// ---------------- attention: all 4 heads, one z-gather ----------------
__global__ __launch_bounds__(256) void k_attn2(const int* __restrict__ klist)
{
    int lane = threadIdx.x & 63;
    int wid = blockIdx.x * 4 + (threadIdx.x >> 6);
    int nw = gridDim.x * 4;
    for (int e = wid; e < EE; e += nw) {
        int kv = (lane < 32) ? klist[(size_t)e * 32 + lane] : -1;
        float zk[16];
#pragma unroll
        for (int j = 0; j < 16; j++) {
            int ij = __shfl(kv, j);
            zk[j] = (ij >= 0) ? us2f(g_z16[(size_t)ij * 64 + lane]) : 0.f;
        }
        for (int hd = 0; hd < 4; hd++) {
            float qp = us2f(g_qp4[hd][(size_t)e * 64 + lane]);
            float s[16];
#pragma unroll
            for (int j = 0; j < 16; j++) {
                int ij = __shfl(kv, j);
                float sj = 0.f;
                if (ij >= 0) {
                    int jj = __shfl(kv, 16 + j);
                    sj = 0.125f * waveSum(qp * zk[j]) + g_b[(size_t)hd * EE + jj];
                }
                s[j] = sj;
            }
            float mx = s[0];
#pragma unroll
            for (int j = 1; j < 16; j++) mx = fmaxf(mx, s[j]);
            float den = 0.f, tacc = 0.f;
#pragma unroll
            for (int j = 0; j < 16; j++) {
                float ee = __expf(s[j] - mx);
                den += ee;
                tacc += ee * zk[j];
            }
            g_t4[hd][(size_t)e * 64 + lane] = f2bu(tacc / den);
        }
    }
}

// ---------------- x/n/cnt scatter ----------------
__global__ __launch_bounds__(256) void k_scatter(const int* __restrict__ edges, const float* __restrict__ nvecs)
{
    int e = blockIdx.x * 256 + threadIdx.x;
    if (e >= EE) return;
    int r = edges[e], c = edges[EE + e];
    float pu = g_phiu[e];
    float tx = pu * g_phix[e], tn = pu * g_phin[e];
    for (int i = 0; i < 3; i++) {
        atomicAdd(&g_xsum[r * 3 + i], g_cdl[e * 3 + i] * tx);
        atomicAdd(&g_nsum[r * 3 + i], nvecs[c * 3 + i] * tn);
    }
    atomicAdd(&g_cnt[r], 1.f);
}

// ---------------- node finalize ----------------
__global__ __launch_bounds__(256) void k_node(
    const float* __restrict__ h, const float* __restrict__ na,
    const float* __restrict__ coord, const float* __restrict__ nvecs,
    const float* __restrict__ icoord, const float* __restrict__ invecs,
    const float* __restrict__ ob,
    const float* __restrict__ W1, const float* __restrict__ b1,
    const float* __restrict__ W2, const float* __restrict__ b2,
    float* __restrict__ out)
{
    __shared__ u16 sW1[192 * 64], sW2[4096];
    __shared__ float sb1[64], sb2[64];
    int tid = threadIdx.x;
    for (int i = tid; i < 192 * 64; i += 256) sW1[i] = f2bu(W1[i]);
    for (int i = tid; i < 4096; i += 256) sW2[i] = f2bu(W2[i]);
    if (tid < 64) { sb1[tid] = b1[tid]; sb2[tid] = b2[tid]; }
    __syncthreads();
    size_t coff = (size_t)NN * 64;
    size_t noff = coff + (size_t)NN * 3;
    int lane = tid & 63;
    int wid = blockIdx.x * 4 + (tid >> 6);
    int nw = gridDim.x * 4;
    for (int n = wid; n < NN; n += nw) {
        float craw = g_cnt[n];
        float rinv = 1.f / fmaxf(craw, 1.f);
        float hl = h[(size_t)n * 64 + lane];
        float al = na[(size_t)n * 64 + lane];
        float obv = (craw > 0.f) ? ob[lane] : 0.f;
        float ml = g_msum[n * 64 + lane] * rinv + obv;
        float acc = sb1[lane];
        for (int i = 0; i < 64; i++) acc += __shfl(hl, i) * us2f(sW1[i * 64 + lane]);
        for (int i = 0; i < 64; i++) acc += __shfl(al, i) * us2f(sW1[(64 + i) * 64 + lane]);
        for (int i = 0; i < 64; i++) acc += __shfl(ml, i) * us2f(sW1[(128 + i) * 64 + lane]);
        float t = siluf(acc);
        float a2 = sb2[lane];
        for (int i = 0; i < 64; i++) a2 += __shfl(t, i) * us2f(sW2[i * 64 + lane]);
        out[(size_t)n * 64 + lane] = 0.2f * hl + 0.8f * a2;
        if (lane < 3) {
            out[coff + n * 3 + lane] = 0.2f * icoord[n * 3 + lane] + 0.8f * coord[n * 3 + lane]
                                       + g_xsum[n * 3 + lane] * rinv;
        }
        float nl = (lane < 3)
            ? (0.2f * invecs[n * 3 + lane] + 0.8f * nvecs[n * 3 + lane] + g_nsum[n * 3 + lane] * rinv)
            : 0.f;
        float nn = sqrtf(waveSum(nl * nl)) + 1e-8f;
        if (lane < 3) out[noff + n * 3 + lane] = nl / nn;
    }
}

extern "C" void kernel_launch(void* const* d_in, const int* in_sizes, int n_in,
                              void* d_out, int out_size, void* d_ws, size_t ws_size,
                              hipStream_t stream)
{
    const int* edges = (const int*)d_in[43];
    const int* klist = (const int*)d_in[44];
    auto F = [&](int i) { return (const float*)d_in[i]; };

    void *p_t1, *p_chem, *p_p1, *p_pos, *p_z16, *p_qp4, *p_g4, *p_t4, *p_M;
    void *p_b, *p_phiu, *p_phix, *p_phin, *p_msum;
    hipGetSymbolAddress(&p_t1,   HIP_SYMBOL(g_t1));
    hipGetSymbolAddress(&p_chem, HIP_SYMBOL(g_chem));
    hipGetSymbolAddress(&p_p1,   HIP_SYMBOL(g_p1));
    hipGetSymbolAddress(&p_pos,  HIP_SYMBOL(g_pos));
    hipGetSymbolAddress(&p_z16,  HIP_SYMBOL(g_z16));
    hipGetSymbolAddress(&p_qp4,  HIP_SYMBOL(g_qp4));
    hipGetSymbolAddress(&p_g4,   HIP_SYMBOL(g_g4));
    hipGetSymbolAddress(&p_t4,   HIP_SYMBOL(g_t4));
    hipGetSymbolAddress(&p_M,    HIP_SYMBOL(g_M));
    hipGetSymbolAddress(&p_b,    HIP_SYMBOL(g_b));
    hipGetSymbolAddress(&p_phiu, HIP_SYMBOL(g_phiu));
    hipGetSymbolAddress(&p_phix, HIP_SYMBOL(g_phix));
    hipGetSymbolAddress(&p_phin, HIP_SYMBOL(g_phin));
    hipGetSymbolAddress(&p_msum, HIP_SYMBOL(g_msum));

    k_zero<<<512, 256, 0, stream>>>();
    k_prep<<<64, 256, 0, stream>>>(F(19), F(20));
    k_geom<<<1024, 256, 0, stream>>>(F(1), F(2), edges, F(11), F(12));
    k_chem1<<<3125, 256, 0, stream>>>(F(0), F(4), F(3), edges, F(7), F(8));
    // chem = silu(t1 @ ch_W2 + ch_b2)
    k_gemm<M_SILU><<<3125, 256, 0, stream>>>((const u16*)p_t1, d_in[9], F(10),
        nullptr, nullptr, nullptr, nullptr, nullptr, (u16*)p_chem, nullptr);
    // pos = silu(p1 @ pos_W2 + pos_b2)
    k_gemm<M_SILU><<<3125, 256, 0, stream>>>((const u16*)p_p1, d_in[13], F(14),
        nullptr, nullptr, nullptr, nullptr, nullptr, (u16*)p_pos, nullptr);
    // z epilogue: silu(chem@sh_W+sh_b)*pos -> att sigmoid -> z, b(4 heads)
    k_gemm<M_ZEP><<<3125, 256, 0, stream>>>((const u16*)p_chem, d_in[15], F(16),
        p_pos, F(17), F(18), F(22), nullptr, (u16*)p_z16, (float*)p_b);
    // phi_u / phi_x / phi_n row-dots
    k_gemm<M_DOT><<<3125, 256, 0, stream>>>((const u16*)p_chem, d_in[27], F(28),
        d_in[29], F(30), nullptr, nullptr, nullptr, nullptr, (float*)p_phiu);
    k_gemm<M_DOT><<<3125, 256, 0, stream>>>((const u16*)p_pos, d_in[31], F(32),
        d_in[33], F(34), nullptr, nullptr, nullptr, nullptr, (float*)p_phix);
    k_gemm<M_DOT><<<3125, 256, 0, stream>>>((const u16*)p_pos, d_in[35], F(36),
        d_in[37], F(38), nullptr, nullptr, nullptr, nullptr, (float*)p_phin);
    k_scatter<<<782, 256, 0, stream>>>(edges, F(2));
    // per-head projections
    for (int hd = 0; hd < 4; hd++) {
        k_gemm<M_PLAIN><<<3125, 256, 0, stream>>>((const u16*)p_z16, (const u16*)p_M + hd * 4096,
            nullptr, nullptr, nullptr, nullptr, nullptr, nullptr, (u16*)p_qp4 + hd * ES, nullptr);
        k_gemm<M_SIGM><<<3125, 256, 0, stream>>>((const u16*)p_z16, F(23) + hd * 4096,
            F(24) + hd * 64, nullptr, nullptr, nullptr, nullptr, nullptr, (u16*)p_g4 + hd * ES, nullptr);
    }
    k_attn2<<<1024, 256, 0, stream>>>(klist);
    for (int hd = 0; hd < 4; hd++) {
        // u = (t @ Wv) * g  (reuse qp buffer for u)
        k_gemm<M_MULT><<<3125, 256, 0, stream>>>((const u16*)p_t4 + hd * ES, F(21) + hd * 4096,
            nullptr, (const u16*)p_g4 + hd * ES, nullptr, nullptr, nullptr, nullptr,
            (u16*)p_qp4 + hd * ES, nullptr);
        // msum[row] += u @ out_W[hd]
        k_gemm<M_SCAT><<<3125, 256, 0, stream>>>((const u16*)p_qp4 + hd * ES, F(25) + hd * 4096,
            nullptr, nullptr, nullptr, nullptr, nullptr, edges, nullptr, (float*)p_msum);
    }
    k_node<<<640, 256, 0, stream>>>(F(0), F(4), F(1), F(2), F(5), F(6), F(26),
                                    F(39), F(40), F(41), F(42), (float*)d_out);
}

// Round 7
// 1512.723 us; speedup vs baseline: 10.5584x; 1.7129x over previous
//
#include <hip/hip_runtime.h>

typedef unsigned short u16;
typedef unsigned int u32;
typedef __attribute__((ext_vector_type(8))) short s16x8;
typedef __attribute__((ext_vector_type(4))) float f32x4;

#define NN 10000
#define EE 200000
#define ES ((size_t)EE * 64)

#define DEVI __device__ __forceinline__

DEVI float us2f(u16 u) {
    union { u32 i; float f; } v; v.i = ((u32)u) << 16; return v.f;
}
DEVI u16 f2bu(float f) {
    union { float f; u32 i; } v; v.f = f;
    u32 x = v.i;
    return (u16)((x + 0x7fffu + ((x >> 16) & 1u)) >> 16);
}
DEVI float siluf(float x) { return x / (1.f + __expf(-x)); }
DEVI float sigmf(float x) { return 1.f / (1.f + __expf(-x)); }
DEVI float waveSum(float v) {
#pragma unroll
    for (int o = 32; o; o >>= 1) v += __shfl_xor(v, o);
    return v;
}
DEVI float quadSum(float v) {
#pragma unroll
    for (int o = 1; o < 16; o <<= 1) v += __shfl_xor(v, o);
    return v;
}

// ---- module-owned scratch ----
__device__ u16 g_t1[ES];
__device__ u16 g_chem[ES];
__device__ u16 g_p1[ES];
__device__ u16 g_pos[ES];
__device__ u16 g_z16[ES];
__device__ u16 g_qp4[4][ES];
__device__ u16 g_g4[4][ES];
__device__ u16 g_t4[4][ES];
__device__ u16 g_M[4 * 4096];     // Wq Wk^T per head, [hd][k][n]
__device__ float g_b[4 * (size_t)EE];
__device__ float g_phiu[EE], g_phix[EE], g_phin[EE];
__device__ float g_cdl[EE * 3];
__device__ float g_msum[NN * 64];
__device__ float g_xsum[NN * 3];
__device__ float g_nsum[NN * 3];
__device__ float g_cnt[NN];

// ---------------- zero accumulators ----------------
__global__ __launch_bounds__(256) void k_zero()
{
    int t = blockIdx.x * 256 + threadIdx.x;
    int nt = gridDim.x * 256;
    for (int i = t; i < NN * 64; i += nt) g_msum[i] = 0.f;
    for (int i = t; i < NN * 3; i += nt) { g_xsum[i] = 0.f; g_nsum[i] = 0.f; }
    for (int i = t; i < NN; i += nt) g_cnt[i] = 0.f;
}

// ---------------- M[hd][k][n] = sum_d Wq[hd][k][d] * Wk[hd][n][d] ----------------
__global__ __launch_bounds__(256) void k_prep(const float* __restrict__ Wq, const float* __restrict__ Wk)
{
    int t = blockIdx.x * 256 + threadIdx.x;
    int hd = t >> 12, rem = t & 4095, k = rem >> 6, n = rem & 63;
    const float* wq = Wq + (size_t)hd * 4096 + k * 64;
    const float* wk = Wk + (size_t)hd * 4096 + n * 64;
    float acc = 0.f;
    for (int d = 0; d < 64; d++) acc += wq[d] * wk[d];
    g_M[t] = f2bu(acc);
}

// ---------------- geometry + pos layer1 ----------------
__global__ __launch_bounds__(256) void k_geom(
    const float* __restrict__ coord, const float* __restrict__ nvecs,
    const int* __restrict__ edges, const float* __restrict__ pW1, const float* __restrict__ pb1)
{
    int lane = threadIdx.x & 63;
    int wid = blockIdx.x * 4 + (threadIdx.x >> 6);
    int nw = gridDim.x * 4;
    float w0 = pW1[lane], w1 = pW1[64 + lane], b0 = pb1[lane];
    for (int e = wid; e < EE; e += nw) {
        int r = edges[e], c = edges[EE + e];
        float dl = (lane < 3) ? (coord[r * 3 + lane] - coord[c * 3 + lane]) : 0.f;
        float radial = waveSum(dl * dl);
        float nvr = (lane < 3) ? nvecs[r * 3 + lane] : 0.f;
        float nvc = (lane < 3) ? nvecs[c * 3 + lane] : 0.f;
        float nprod = waveSum(nvr * nvc);
        if (lane < 3) g_cdl[e * 3 + lane] = dl / (sqrtf(radial) + 1e-8f);
        g_p1[(size_t)e * 64 + lane] = f2bu(siluf(b0 + nprod * w0 + radial * w1));
    }
}

// ---------------- chem layer1: gathered-A GEMM, K=288 ----------------
__global__ __launch_bounds__(256) void k_chem1(
    const float* __restrict__ h, const float* __restrict__ na, const float* __restrict__ ea,
    const int* __restrict__ edges, const float* __restrict__ W1, const float* __restrict__ b1)
{
    __shared__ u16 sBT[64 * 296];
    int tid = threadIdx.x;
    for (int i = tid; i < 64 * 296; i += 256) {
        int n = i / 296, k = i - n * 296;
        sBT[i] = (k < 272) ? f2bu(W1[k * 64 + n]) : (u16)0;
    }
    __syncthreads();
    int lane = tid & 63, q = lane >> 4, ln = lane & 15, w = tid >> 6;
    int m0 = blockIdx.x * 64 + w * 16;
    int e = m0 + ln;
    int r_ = edges[e], c_ = edges[EE + e];
    f32x4 acc[4];
#pragma unroll
    for (int t = 0; t < 4; t++) acc[t] = (f32x4){0.f, 0.f, 0.f, 0.f};
#pragma unroll
    for (int k0 = 0; k0 < 9; k0++) {
        int k = k0 * 32 + q * 8;
        s16x8 af = {0, 0, 0, 0, 0, 0, 0, 0};
        const float* p = nullptr;
        if (k < 64)       p = h  + (size_t)r_ * 64 + k;
        else if (k < 128) p = h  + (size_t)c_ * 64 + (k - 64);
        else if (k < 192) p = na + (size_t)r_ * 64 + (k - 128);
        else if (k < 256) p = na + (size_t)c_ * 64 + (k - 192);
        else if (k < 272) p = ea + (size_t)e * 16 + (k - 256);
        if (p) {
            float4 f0 = *(const float4*)(p);
            float4 f1 = *(const float4*)(p + 4);
            af[0] = (short)f2bu(f0.x); af[1] = (short)f2bu(f0.y);
            af[2] = (short)f2bu(f0.z); af[3] = (short)f2bu(f0.w);
            af[4] = (short)f2bu(f1.x); af[5] = (short)f2bu(f1.y);
            af[6] = (short)f2bu(f1.z); af[7] = (short)f2bu(f1.w);
        }
#pragma unroll
        for (int t = 0; t < 4; t++) {
            s16x8 bf = *(const s16x8*)(&sBT[(t * 16 + ln) * 296 + k0 * 32 + q * 8]);
            acc[t] = __builtin_amdgcn_mfma_f32_16x16x32_bf16(af, bf, acc[t], 0, 0, 0);
        }
    }
#pragma unroll
    for (int t = 0; t < 4; t++) {
        float bv = b1[t * 16 + ln];
#pragma unroll
        for (int r = 0; r < 4; r++)
            g_t1[(size_t)(m0 + q * 4 + r) * 64 + t * 16 + ln] = f2bu(siluf(acc[t][r] + bv));
    }
}

// ---------------- generic K=64, N=64 GEMM with fused epilogues ----------------
#define M_SILU 0
#define M_ZEP 4
#define M_DOT 5

template<int MODE>
__global__ __launch_bounds__(256) void k_gemm(
    const u16* __restrict__ A, const void* __restrict__ Bv,
    const float* __restrict__ bias,
    const void* __restrict__ aux,        // ZEP: pos(u16); DOT: w2(f32)
    const float* __restrict__ aux2,      // ZEP: attW; DOT: b2
    const float* __restrict__ aux3,      // ZEP: attb
    const float* __restrict__ aux4,      // ZEP: Wb[4][64]
    u16* __restrict__ outb, float* __restrict__ outf)
{
    __shared__ u16 sBT[64 * 72];
    int tid = threadIdx.x;
    for (int i = tid; i < 4096; i += 256) {
        int k = i >> 6, n = i & 63;
        sBT[n * 72 + k] = f2bu(((const float*)Bv)[i]);
    }
    __syncthreads();
    int lane = tid & 63, q = lane >> 4, ln = lane & 15, w = tid >> 6;
    int m0 = blockIdx.x * 64 + w * 16;
    f32x4 acc[4];
#pragma unroll
    for (int t = 0; t < 4; t++) acc[t] = (f32x4){0.f, 0.f, 0.f, 0.f};
    const u16* ar = A + (size_t)(m0 + ln) * 64;
#pragma unroll
    for (int k0 = 0; k0 < 2; k0++) {
        s16x8 af = *(const s16x8*)(ar + k0 * 32 + q * 8);
#pragma unroll
        for (int t = 0; t < 4; t++) {
            s16x8 bf = *(const s16x8*)(&sBT[(t * 16 + ln) * 72 + k0 * 32 + q * 8]);
            acc[t] = __builtin_amdgcn_mfma_f32_16x16x32_bf16(af, bf, acc[t], 0, 0, 0);
        }
    }
    int rows[4];
#pragma unroll
    for (int r = 0; r < 4; r++) rows[r] = m0 + q * 4 + r;
    float bv[4];
#pragma unroll
    for (int t = 0; t < 4; t++) bv[t] = bias ? bias[t * 16 + ln] : 0.f;

    if (MODE == M_SILU) {
#pragma unroll
        for (int t = 0; t < 4; t++)
#pragma unroll
            for (int r = 0; r < 4; r++)
                outb[(size_t)rows[r] * 64 + t * 16 + ln] = f2bu(siluf(acc[t][r] + bv[t]));
    } else if (MODE == M_ZEP) {
        float zv[4][4];
        float part[4] = {0.f, 0.f, 0.f, 0.f};
#pragma unroll
        for (int t = 0; t < 4; t++) {
            float aw = aux2[t * 16 + ln];
#pragma unroll
            for (int r = 0; r < 4; r++) {
                float o = siluf(acc[t][r] + bv[t]) * us2f(((const u16*)aux)[(size_t)rows[r] * 64 + t * 16 + ln]);
                zv[t][r] = o;
                part[r] += o * aw;
            }
        }
        float ab = aux3[0];
#pragma unroll
        for (int r = 0; r < 4; r++) {
            float sg = sigmf(quadSum(part[r]) + ab);
#pragma unroll
            for (int t = 0; t < 4; t++) {
                float z = zv[t][r] * sg;
                zv[t][r] = z;
                outb[(size_t)rows[r] * 64 + t * 16 + ln] = f2bu(z);
            }
        }
#pragma unroll
        for (int hd = 0; hd < 4; hd++) {
#pragma unroll
            for (int r = 0; r < 4; r++) {
                float p = 0.f;
#pragma unroll
                for (int t = 0; t < 4; t++) p += zv[t][r] * aux4[hd * 64 + t * 16 + ln];
                p = quadSum(p);
                if (ln == hd) outf[(size_t)hd * EE + rows[r]] = p;
            }
        }
    } else if (MODE == M_DOT) {
        float part[4] = {0.f, 0.f, 0.f, 0.f};
#pragma unroll
        for (int t = 0; t < 4; t++) {
            float w2 = ((const float*)aux)[t * 16 + ln];
#pragma unroll
            for (int r = 0; r < 4; r++) part[r] += siluf(acc[t][r] + bv[t]) * w2;
        }
        float b2 = aux2[0];
#pragma unroll
        for (int r = 0; r < 4; r++) {
            float s = quadSum(part[r]) + b2;
            if (ln == 0) outf[rows[r]] = s;
        }
    }
}

// ---------------- qp + gate, all heads via blockIdx.y ----------------
__global__ __launch_bounds__(256) void k_qg(const float* __restrict__ Wg, const float* __restrict__ bg)
{
    int hd = blockIdx.y;
    __shared__ u16 sM[64 * 72], sG[64 * 72];
    int tid = threadIdx.x;
    for (int i = tid; i < 4096; i += 256) {
        int k = i >> 6, n = i & 63;
        sM[n * 72 + k] = g_M[hd * 4096 + i];
        sG[n * 72 + k] = f2bu(Wg[(size_t)hd * 4096 + i]);
    }
    __syncthreads();
    int lane = tid & 63, q = lane >> 4, ln = lane & 15, w = tid >> 6;
    int m0 = blockIdx.x * 64 + w * 16;
    f32x4 aM[4], aG[4];
#pragma unroll
    for (int t = 0; t < 4; t++) { aM[t] = (f32x4){0,0,0,0}; aG[t] = (f32x4){0,0,0,0}; }
    const u16* ar = g_z16 + (size_t)(m0 + ln) * 64;
#pragma unroll
    for (int k0 = 0; k0 < 2; k0++) {
        s16x8 af = *(const s16x8*)(ar + k0 * 32 + q * 8);
#pragma unroll
        for (int t = 0; t < 4; t++) {
            s16x8 bm = *(const s16x8*)(&sM[(t * 16 + ln) * 72 + k0 * 32 + q * 8]);
            s16x8 bg_ = *(const s16x8*)(&sG[(t * 16 + ln) * 72 + k0 * 32 + q * 8]);
            aM[t] = __builtin_amdgcn_mfma_f32_16x16x32_bf16(af, bm, aM[t], 0, 0, 0);
            aG[t] = __builtin_amdgcn_mfma_f32_16x16x32_bf16(af, bg_, aG[t], 0, 0, 0);
        }
    }
#pragma unroll
    for (int t = 0; t < 4; t++) {
        float bb = bg[hd * 64 + t * 16 + ln];
#pragma unroll
        for (int r = 0; r < 4; r++) {
            size_t idx = (size_t)(m0 + q * 4 + r) * 64 + t * 16 + ln;
            g_qp4[hd][idx] = f2bu(aM[t][r]);
            g_g4[hd][idx] = f2bu(sigmf(aG[t][r] + bb));
        }
    }
}

// ---------------- attention: MFMA scores, scalar PV ----------------
__global__ __launch_bounds__(256) void k_attn2(const int* __restrict__ klist)
{
    __shared__ __align__(16) float sA[4][4][16];   // [wave][hd][j]
    int tid = threadIdx.x;
    int w = tid >> 6, lane = tid & 63, q = lane >> 4, ln = lane & 15;
    int wid = blockIdx.x * 4 + w;
    int nw = gridDim.x * 4;
    for (int e = wid; e < EE; e += nw) {
        int kv = (lane < 32) ? klist[(size_t)e * 32 + lane] : -1;
        int ij_ln = __shfl(kv, ln);
        s16x8 za0 = {0,0,0,0,0,0,0,0}, za1 = {0,0,0,0,0,0,0,0};
        if (ij_ln >= 0) {
            const u16* zr = g_z16 + (size_t)ij_ln * 64;
            za0 = *(const s16x8*)(zr + q * 8);
            za1 = *(const s16x8*)(zr + 32 + q * 8);
        }
        s16x8 qb0 = {0,0,0,0,0,0,0,0}, qb1 = {0,0,0,0,0,0,0,0};
        if (ln < 4) {
            const u16* qr = &g_qp4[ln][(size_t)e * 64];
            qb0 = *(const s16x8*)(qr + q * 8);
            qb1 = *(const s16x8*)(qr + 32 + q * 8);
        }
        f32x4 sc = (f32x4){0.f, 0.f, 0.f, 0.f};
        sc = __builtin_amdgcn_mfma_f32_16x16x32_bf16(za0, qb0, sc, 0, 0, 0);
        sc = __builtin_amdgcn_mfma_f32_16x16x32_bf16(za1, qb1, sc, 0, 0, 0);
        // lane holds s[j = q*4+r][hd = ln]
        float s[4];
#pragma unroll
        for (int r = 0; r < 4; r++) {
            int j = q * 4 + r;
            int ij = __shfl(kv, j);
            int jj = __shfl(kv, 16 + j);
            float bvl = (ij >= 0 && ln < 4) ? g_b[(size_t)ln * EE + jj] : 0.f;
            s[r] = (ij >= 0) ? (0.125f * sc[r] + bvl) : 0.f;
        }
        float mx = fmaxf(fmaxf(s[0], s[1]), fmaxf(s[2], s[3]));
        mx = fmaxf(mx, __shfl_xor(mx, 16));
        mx = fmaxf(mx, __shfl_xor(mx, 32));
        float ex[4], ps = 0.f;
#pragma unroll
        for (int r = 0; r < 4; r++) { ex[r] = __expf(s[r] - mx); ps += ex[r]; }
        ps += __shfl_xor(ps, 16);
        ps += __shfl_xor(ps, 32);
        float inv = 1.f / ps;
        if (ln < 4)
            *(f32x4*)&sA[w][ln][q * 4] = (f32x4){ex[0] * inv, ex[1] * inv, ex[2] * inv, ex[3] * inv};
        asm volatile("s_waitcnt lgkmcnt(0)" ::: "memory");
        // old-layout gather for PV (lane = feature d)
        float zk[16];
#pragma unroll
        for (int j = 0; j < 16; j++) {
            int ij = __shfl(kv, j);
            zk[j] = (ij >= 0) ? us2f(g_z16[(size_t)ij * 64 + lane]) : 0.f;
        }
        float t0 = 0.f, t1 = 0.f, t2 = 0.f, t3 = 0.f;
#pragma unroll
        for (int j4 = 0; j4 < 4; j4++) {
            f32x4 a0 = *(const f32x4*)&sA[w][0][j4 * 4];
            f32x4 a1 = *(const f32x4*)&sA[w][1][j4 * 4];
            f32x4 a2 = *(const f32x4*)&sA[w][2][j4 * 4];
            f32x4 a3 = *(const f32x4*)&sA[w][3][j4 * 4];
#pragma unroll
            for (int r = 0; r < 4; r++) {
                float zz = zk[j4 * 4 + r];
                t0 += a0[r] * zz; t1 += a1[r] * zz; t2 += a2[r] * zz; t3 += a3[r] * zz;
            }
        }
        size_t ob = (size_t)e * 64 + lane;
        g_t4[0][ob] = f2bu(t0);
        g_t4[1][ob] = f2bu(t1);
        g_t4[2][ob] = f2bu(t2);
        g_t4[3][ob] = f2bu(t3);
    }
}

// ---------------- u = (t @ Wv) * g ; msum += u @ out_W (chained, via LDS) ----------------
__global__ __launch_bounds__(256) void k_us(
    const float* __restrict__ Wv, const float* __restrict__ oW, const int* __restrict__ edges)
{
    int hd = blockIdx.y;
    __shared__ u16 sV[64 * 72], sO[64 * 72], sU[64 * 72];
    int tid = threadIdx.x;
    for (int i = tid; i < 4096; i += 256) {
        int k = i >> 6, n = i & 63;
        sV[n * 72 + k] = f2bu(Wv[(size_t)hd * 4096 + i]);
        sO[n * 72 + k] = f2bu(oW[(size_t)hd * 4096 + i]);
    }
    __syncthreads();
    int lane = tid & 63, q = lane >> 4, ln = lane & 15, w = tid >> 6;
    int m0 = blockIdx.x * 64 + w * 16;
    f32x4 acc[4];
#pragma unroll
    for (int t = 0; t < 4; t++) acc[t] = (f32x4){0,0,0,0};
    const u16* ar = &g_t4[hd][(size_t)(m0 + ln) * 64];
#pragma unroll
    for (int k0 = 0; k0 < 2; k0++) {
        s16x8 af = *(const s16x8*)(ar + k0 * 32 + q * 8);
#pragma unroll
        for (int t = 0; t < 4; t++) {
            s16x8 bf = *(const s16x8*)(&sV[(t * 16 + ln) * 72 + k0 * 32 + q * 8]);
            acc[t] = __builtin_amdgcn_mfma_f32_16x16x32_bf16(af, bf, acc[t], 0, 0, 0);
        }
    }
#pragma unroll
    for (int t = 0; t < 4; t++)
#pragma unroll
        for (int r = 0; r < 4; r++) {
            size_t row = m0 + q * 4 + r;
            float u = acc[t][r] * us2f(g_g4[hd][row * 64 + t * 16 + ln]);
            sU[(w * 16 + q * 4 + r) * 72 + t * 16 + ln] = f2bu(u);
        }
    __syncthreads();
    f32x4 a2[4];
#pragma unroll
    for (int t = 0; t < 4; t++) a2[t] = (f32x4){0,0,0,0};
#pragma unroll
    for (int k0 = 0; k0 < 2; k0++) {
        s16x8 af = *(const s16x8*)(&sU[(w * 16 + ln) * 72 + k0 * 32 + q * 8]);
#pragma unroll
        for (int t = 0; t < 4; t++) {
            s16x8 bf = *(const s16x8*)(&sO[(t * 16 + ln) * 72 + k0 * 32 + q * 8]);
            a2[t] = __builtin_amdgcn_mfma_f32_16x16x32_bf16(af, bf, a2[t], 0, 0, 0);
        }
    }
#pragma unroll
    for (int r = 0; r < 4; r++) {
        int dst = edges[m0 + q * 4 + r] * 64;
#pragma unroll
        for (int t = 0; t < 4; t++) atomicAdd(&g_msum[dst + t * 16 + ln], a2[t][r]);
    }
}

// ---------------- x/n/cnt scatter ----------------
__global__ __launch_bounds__(256) void k_scatter(const int* __restrict__ edges, const float* __restrict__ nvecs)
{
    int e = blockIdx.x * 256 + threadIdx.x;
    if (e >= EE) return;
    int r = edges[e], c = edges[EE + e];
    float pu = g_phiu[e];
    float tx = pu * g_phix[e], tn = pu * g_phin[e];
    for (int i = 0; i < 3; i++) {
        atomicAdd(&g_xsum[r * 3 + i], g_cdl[e * 3 + i] * tx);
        atomicAdd(&g_nsum[r * 3 + i], nvecs[c * 3 + i] * tn);
    }
    atomicAdd(&g_cnt[r], 1.f);
}

// ---------------- node finalize ----------------
__global__ __launch_bounds__(256) void k_node(
    const float* __restrict__ h, const float* __restrict__ na,
    const float* __restrict__ coord, const float* __restrict__ nvecs,
    const float* __restrict__ icoord, const float* __restrict__ invecs,
    const float* __restrict__ ob,
    const float* __restrict__ W1, const float* __restrict__ b1,
    const float* __restrict__ W2, const float* __restrict__ b2,
    float* __restrict__ out)
{
    __shared__ u16 sW1[192 * 64], sW2[4096];
    __shared__ float sb1[64], sb2[64];
    int tid = threadIdx.x;
    for (int i = tid; i < 192 * 64; i += 256) sW1[i] = f2bu(W1[i]);
    for (int i = tid; i < 4096; i += 256) sW2[i] = f2bu(W2[i]);
    if (tid < 64) { sb1[tid] = b1[tid]; sb2[tid] = b2[tid]; }
    __syncthreads();
    size_t coff = (size_t)NN * 64;
    size_t noff = coff + (size_t)NN * 3;
    int lane = tid & 63;
    int wid = blockIdx.x * 4 + (tid >> 6);
    int nw = gridDim.x * 4;
    for (int n = wid; n < NN; n += nw) {
        float craw = g_cnt[n];
        float rinv = 1.f / fmaxf(craw, 1.f);
        float hl = h[(size_t)n * 64 + lane];
        float al = na[(size_t)n * 64 + lane];
        float obv = (craw > 0.f) ? ob[lane] : 0.f;
        float ml = g_msum[n * 64 + lane] * rinv + obv;
        float acc = sb1[lane];
        for (int i = 0; i < 64; i++) acc += __shfl(hl, i) * us2f(sW1[i * 64 + lane]);
        for (int i = 0; i < 64; i++) acc += __shfl(al, i) * us2f(sW1[(64 + i) * 64 + lane]);
        for (int i = 0; i < 64; i++) acc += __shfl(ml, i) * us2f(sW1[(128 + i) * 64 + lane]);
        float t = siluf(acc);
        float a2 = sb2[lane];
        for (int i = 0; i < 64; i++) a2 += __shfl(t, i) * us2f(sW2[i * 64 + lane]);
        out[(size_t)n * 64 + lane] = 0.2f * hl + 0.8f * a2;
        if (lane < 3) {
            out[coff + n * 3 + lane] = 0.2f * icoord[n * 3 + lane] + 0.8f * coord[n * 3 + lane]
                                       + g_xsum[n * 3 + lane] * rinv;
        }
        float nl = (lane < 3)
            ? (0.2f * invecs[n * 3 + lane] + 0.8f * nvecs[n * 3 + lane] + g_nsum[n * 3 + lane] * rinv)
            : 0.f;
        float nn = sqrtf(waveSum(nl * nl)) + 1e-8f;
        if (lane < 3) out[noff + n * 3 + lane] = nl / nn;
    }
}

extern "C" void kernel_launch(void* const* d_in, const int* in_sizes, int n_in,
                              void* d_out, int out_size, void* d_ws, size_t ws_size,
                              hipStream_t stream)
{
    const int* edges = (const int*)d_in[43];
    const int* klist = (const int*)d_in[44];
    auto F = [&](int i) { return (const float*)d_in[i]; };

    void *p_t1, *p_chem, *p_p1, *p_pos, *p_z16, *p_b, *p_phiu, *p_phix, *p_phin;
    hipGetSymbolAddress(&p_t1,   HIP_SYMBOL(g_t1));
    hipGetSymbolAddress(&p_chem, HIP_SYMBOL(g_chem));
    hipGetSymbolAddress(&p_p1,   HIP_SYMBOL(g_p1));
    hipGetSymbolAddress(&p_pos,  HIP_SYMBOL(g_pos));
    hipGetSymbolAddress(&p_z16,  HIP_SYMBOL(g_z16));
    hipGetSymbolAddress(&p_b,    HIP_SYMBOL(g_b));
    hipGetSymbolAddress(&p_phiu, HIP_SYMBOL(g_phiu));
    hipGetSymbolAddress(&p_phix, HIP_SYMBOL(g_phix));
    hipGetSymbolAddress(&p_phin, HIP_SYMBOL(g_phin));

    k_zero<<<512, 256, 0, stream>>>();
    k_prep<<<64, 256, 0, stream>>>(F(19), F(20));
    k_geom<<<1024, 256, 0, stream>>>(F(1), F(2), edges, F(11), F(12));
    k_chem1<<<3125, 256, 0, stream>>>(F(0), F(4), F(3), edges, F(7), F(8));
    k_gemm<M_SILU><<<3125, 256, 0, stream>>>((const u16*)p_t1, d_in[9], F(10),
        nullptr, nullptr, nullptr, nullptr, (u16*)p_chem, nullptr);
    k_gemm<M_SILU><<<3125, 256, 0, stream>>>((const u16*)p_p1, d_in[13], F(14),
        nullptr, nullptr, nullptr, nullptr, (u16*)p_pos, nullptr);
    k_gemm<M_ZEP><<<3125, 256, 0, stream>>>((const u16*)p_chem, d_in[15], F(16),
        p_pos, F(17), F(18), F(22), (u16*)p_z16, (float*)p_b);
    k_gemm<M_DOT><<<3125, 256, 0, stream>>>((const u16*)p_chem, d_in[27], F(28),
        d_in[29], F(30), nullptr, nullptr, nullptr, (float*)p_phiu);
    k_gemm<M_DOT><<<3125, 256, 0, stream>>>((const u16*)p_pos, d_in[31], F(32),
        d_in[33], F(34), nullptr, nullptr, nullptr, (float*)p_phix);
    k_gemm<M_DOT><<<3125, 256, 0, stream>>>((const u16*)p_pos, d_in[35], F(36),
        d_in[37], F(38), nullptr, nullptr, nullptr, (float*)p_phin);
    k_scatter<<<782, 256, 0, stream>>>(edges, F(2));
    k_qg<<<dim3(3125, 4), 256, 0, stream>>>(F(23), F(24));
    k_attn2<<<2048, 256, 0, stream>>>(klist);
    k_us<<<dim3(3125, 4), 256, 0, stream>>>(F(21), F(25), edges);
    k_node<<<640, 256, 0, stream>>>(F(0), F(4), F(1), F(2), F(5), F(6), F(26),
                                    F(39), F(40), F(41), F(42), (float*)d_out);
}

// Round 8
// 1252.462 us; speedup vs baseline: 12.7524x; 1.2078x over previous
//
#include <hip/hip_runtime.h>

typedef unsigned short u16;
typedef unsigned int u32;
typedef __attribute__((ext_vector_type(8))) short s16x8;
typedef __attribute__((ext_vector_type(4))) float f32x4;

#define NN 10000
#define EE 200000
#define ES ((size_t)EE * 64)

#define DEVI __device__ __forceinline__

DEVI float us2f(u16 u) {
    union { u32 i; float f; } v; v.i = ((u32)u) << 16; return v.f;
}
DEVI u16 f2bu(float f) {
    union { float f; u32 i; } v; v.f = f;
    u32 x = v.i;
    return (u16)((x + 0x7fffu + ((x >> 16) & 1u)) >> 16);
}
DEVI float siluf(float x) { return x / (1.f + __expf(-x)); }
DEVI float sigmf(float x) { return 1.f / (1.f + __expf(-x)); }
DEVI float waveSum(float v) {
#pragma unroll
    for (int o = 32; o; o >>= 1) v += __shfl_xor(v, o);
    return v;
}
DEVI float quadSum(float v) {
#pragma unroll
    for (int o = 1; o < 16; o <<= 1) v += __shfl_xor(v, o);
    return v;
}

// ---- module-owned scratch ----
__device__ u16 g_t1[ES];          // chem layer1 out
__device__ u16 g_p1[ES];          // pos layer1 out
__device__ u16 g_z16[ES];
__device__ u16 g_qp4[4][ES];      // per-head q-projected
__device__ u16 g_g4[4][ES];       // per-head gate
__device__ u16 g_t4[4][ES];       // per-head aggregated z
__device__ u16 g_M[4 * 4096];     // Wq Wk^T per head, [hd][k][n]
__device__ float g_b4[(size_t)EE * 4];   // [e][hd]
__device__ float g_phiu[EE];
__device__ float g_cdl[EE * 3];
__device__ float g_msum[NN * 64];
__device__ float g_xsum[NN * 3];
__device__ float g_nsum[NN * 3];
__device__ float g_cnt[NN];

// ---------------- M precompute + accumulator zeroing (merged) ----------------
__global__ __launch_bounds__(256) void k_prep(const float* __restrict__ Wq, const float* __restrict__ Wk)
{
    int t = blockIdx.x * 256 + threadIdx.x;
    if (t < 16384) {
        int hd = t >> 12, rem = t & 4095, k = rem >> 6, n = rem & 63;
        const float* wq = Wq + (size_t)hd * 4096 + k * 64;
        const float* wk = Wk + (size_t)hd * 4096 + n * 64;
        float acc = 0.f;
        for (int d = 0; d < 64; d++) acc += wq[d] * wk[d];
        g_M[t] = f2bu(acc);
    }
    int nt = gridDim.x * 256;
    for (int i = t; i < NN * 64; i += nt) g_msum[i] = 0.f;
    for (int i = t; i < NN * 3; i += nt) { g_xsum[i] = 0.f; g_nsum[i] = 0.f; }
    for (int i = t; i < NN; i += nt) g_cnt[i] = 0.f;
}

// ---------------- geometry + pos layer1 ----------------
__global__ __launch_bounds__(256) void k_geom(
    const float* __restrict__ coord, const float* __restrict__ nvecs,
    const int* __restrict__ edges, const float* __restrict__ pW1, const float* __restrict__ pb1)
{
    int lane = threadIdx.x & 63;
    int wid = blockIdx.x * 4 + (threadIdx.x >> 6);
    int nw = gridDim.x * 4;
    float w0 = pW1[lane], w1 = pW1[64 + lane], b0 = pb1[lane];
    for (int e = wid; e < EE; e += nw) {
        int r = edges[e], c = edges[EE + e];
        float dl = (lane < 3) ? (coord[r * 3 + lane] - coord[c * 3 + lane]) : 0.f;
        float radial = waveSum(dl * dl);
        float nvr = (lane < 3) ? nvecs[r * 3 + lane] : 0.f;
        float nvc = (lane < 3) ? nvecs[c * 3 + lane] : 0.f;
        float nprod = waveSum(nvr * nvc);
        if (lane < 3) g_cdl[e * 3 + lane] = dl / (sqrtf(radial) + 1e-8f);
        g_p1[(size_t)e * 64 + lane] = f2bu(siluf(b0 + nprod * w0 + radial * w1));
    }
}

// ---------------- chem layer1: gathered-A GEMM, K=288 ----------------
__global__ __launch_bounds__(256) void k_chem1(
    const float* __restrict__ h, const float* __restrict__ na, const float* __restrict__ ea,
    const int* __restrict__ edges, const float* __restrict__ W1, const float* __restrict__ b1)
{
    __shared__ u16 sBT[64 * 296];
    int tid = threadIdx.x;
    for (int i = tid; i < 64 * 296; i += 256) {
        int n = i / 296, k = i - n * 296;
        sBT[i] = (k < 272) ? f2bu(W1[k * 64 + n]) : (u16)0;
    }
    __syncthreads();
    int lane = tid & 63, q = lane >> 4, ln = lane & 15, w = tid >> 6;
    int m0 = blockIdx.x * 64 + w * 16;
    int e = m0 + ln;
    int r_ = edges[e], c_ = edges[EE + e];
    f32x4 acc[4];
#pragma unroll
    for (int t = 0; t < 4; t++) acc[t] = (f32x4){0.f, 0.f, 0.f, 0.f};
#pragma unroll
    for (int k0 = 0; k0 < 9; k0++) {
        int k = k0 * 32 + q * 8;
        s16x8 af = {0, 0, 0, 0, 0, 0, 0, 0};
        const float* p = nullptr;
        if (k < 64)       p = h  + (size_t)r_ * 64 + k;
        else if (k < 128) p = h  + (size_t)c_ * 64 + (k - 64);
        else if (k < 192) p = na + (size_t)r_ * 64 + (k - 128);
        else if (k < 256) p = na + (size_t)c_ * 64 + (k - 192);
        else if (k < 272) p = ea + (size_t)e * 16 + (k - 256);
        if (p) {
            float4 f0 = *(const float4*)(p);
            float4 f1 = *(const float4*)(p + 4);
            af[0] = (short)f2bu(f0.x); af[1] = (short)f2bu(f0.y);
            af[2] = (short)f2bu(f0.z); af[3] = (short)f2bu(f0.w);
            af[4] = (short)f2bu(f1.x); af[5] = (short)f2bu(f1.y);
            af[6] = (short)f2bu(f1.z); af[7] = (short)f2bu(f1.w);
        }
#pragma unroll
        for (int t = 0; t < 4; t++) {
            s16x8 bf = *(const s16x8*)(&sBT[(t * 16 + ln) * 296 + k0 * 32 + q * 8]);
            acc[t] = __builtin_amdgcn_mfma_f32_16x16x32_bf16(af, bf, acc[t], 0, 0, 0);
        }
    }
#pragma unroll
    for (int t = 0; t < 4; t++) {
        float bv = b1[t * 16 + ln];
#pragma unroll
        for (int r = 0; r < 4; r++)
            g_t1[(size_t)(m0 + q * 4 + r) * 64 + t * 16 + ln] = f2bu(siluf(acc[t][r] + bv));
    }
}

// helper: stage a 64x64 f32 weight as bf16 [n][k] stride-72 tile
DEVI void stageW(u16* dst, const float* src, int tid) {
    for (int i = tid; i < 4096; i += 256) {
        int k = i >> 6, n = i & 63;
        dst[n * 72 + k] = f2bu(src[i]);
    }
}

// ---------------- MegaA: pos, chem -> z, b4, phiu ----------------
__global__ __launch_bounds__(256) void k_megaA(
    const float* __restrict__ chW2, const float* __restrict__ chb2,
    const float* __restrict__ posW2, const float* __restrict__ posb2,
    const float* __restrict__ shW, const float* __restrict__ shb,
    const float* __restrict__ attW, const float* __restrict__ attb,
    const float* __restrict__ Wb,
    const float* __restrict__ uW1, const float* __restrict__ ub1,
    const float* __restrict__ uW2, const float* __restrict__ ub2)
{
    __shared__ u16 sCH[64 * 72], sPW[64 * 72], sSH[64 * 72], sUW[64 * 72];
    __shared__ u16 T[4][16 * 72];
    __shared__ float sWB[256], sATT[64];
    int tid = threadIdx.x;
    stageW(sCH, chW2, tid); stageW(sPW, posW2, tid);
    stageW(sSH, shW, tid);  stageW(sUW, uW1, tid);
    sWB[tid] = Wb[tid];
    if (tid < 64) sATT[tid] = attW[tid];
    __syncthreads();
    int lane = tid & 63, q = lane >> 4, ln = lane & 15, w = tid >> 6;
    int m0 = blockIdx.x * 64 + w * 16;
    // pos = silu(p1 @ posW2 + posb2)
    f32x4 pacc[4];
#pragma unroll
    for (int t = 0; t < 4; t++) pacc[t] = (f32x4){0,0,0,0};
    {
        const u16* ar = g_p1 + (size_t)(m0 + ln) * 64;
#pragma unroll
        for (int k0 = 0; k0 < 2; k0++) {
            s16x8 af = *(const s16x8*)(ar + k0 * 32 + q * 8);
#pragma unroll
            for (int t = 0; t < 4; t++) {
                s16x8 bf = *(const s16x8*)(&sPW[(t * 16 + ln) * 72 + k0 * 32 + q * 8]);
                pacc[t] = __builtin_amdgcn_mfma_f32_16x16x32_bf16(af, bf, pacc[t], 0, 0, 0);
            }
        }
    }
    float posD[4][4];
#pragma unroll
    for (int t = 0; t < 4; t++) {
        float pb = posb2[t * 16 + ln];
#pragma unroll
        for (int r = 0; r < 4; r++) posD[t][r] = siluf(pacc[t][r] + pb);
    }
    // chem = silu(t1 @ chW2 + chb2) -> transpose to T
    f32x4 cacc[4];
#pragma unroll
    for (int t = 0; t < 4; t++) cacc[t] = (f32x4){0,0,0,0};
    {
        const u16* ar = g_t1 + (size_t)(m0 + ln) * 64;
#pragma unroll
        for (int k0 = 0; k0 < 2; k0++) {
            s16x8 af = *(const s16x8*)(ar + k0 * 32 + q * 8);
#pragma unroll
            for (int t = 0; t < 4; t++) {
                s16x8 bf = *(const s16x8*)(&sCH[(t * 16 + ln) * 72 + k0 * 32 + q * 8]);
                cacc[t] = __builtin_amdgcn_mfma_f32_16x16x32_bf16(af, bf, cacc[t], 0, 0, 0);
            }
        }
    }
#pragma unroll
    for (int t = 0; t < 4; t++) {
        float cb = chb2[t * 16 + ln];
#pragma unroll
        for (int r = 0; r < 4; r++)
            T[w][(q * 4 + r) * 72 + t * 16 + ln] = f2bu(siluf(cacc[t][r] + cb));
    }
    asm volatile("s_waitcnt lgkmcnt(0)" ::: "memory");
    s16x8 ca0 = *(const s16x8*)(&T[w][ln * 72 + q * 8]);
    s16x8 ca1 = *(const s16x8*)(&T[w][ln * 72 + 32 + q * 8]);
    // out = silu(chem @ shW + shb) * pos ; att -> z ; b4
    f32x4 sacc[4];
#pragma unroll
    for (int t = 0; t < 4; t++) {
        f32x4 a = (f32x4){0,0,0,0};
        a = __builtin_amdgcn_mfma_f32_16x16x32_bf16(ca0, *(const s16x8*)(&sSH[(t * 16 + ln) * 72 + q * 8]), a, 0, 0, 0);
        a = __builtin_amdgcn_mfma_f32_16x16x32_bf16(ca1, *(const s16x8*)(&sSH[(t * 16 + ln) * 72 + 32 + q * 8]), a, 0, 0, 0);
        sacc[t] = a;
    }
    float zv[4][4];
    float part[4] = {0.f, 0.f, 0.f, 0.f};
#pragma unroll
    for (int t = 0; t < 4; t++) {
        float sb = shb[t * 16 + ln];
        float aw = sATT[t * 16 + ln];
#pragma unroll
        for (int r = 0; r < 4; r++) {
            float o = siluf(sacc[t][r] + sb) * posD[t][r];
            zv[t][r] = o;
            part[r] += o * aw;
        }
    }
    float ab = attb[0];
#pragma unroll
    for (int r = 0; r < 4; r++) {
        float sg = sigmf(quadSum(part[r]) + ab);
        size_t row = m0 + q * 4 + r;
#pragma unroll
        for (int t = 0; t < 4; t++) {
            float z = zv[t][r] * sg;
            zv[t][r] = z;
            g_z16[row * 64 + t * 16 + ln] = f2bu(z);
        }
    }
#pragma unroll
    for (int hd = 0; hd < 4; hd++) {
#pragma unroll
        for (int r = 0; r < 4; r++) {
            float p = 0.f;
#pragma unroll
            for (int t = 0; t < 4; t++) p += zv[t][r] * sWB[hd * 64 + t * 16 + ln];
            p = quadSum(p);
            if (ln == hd) g_b4[(size_t)(m0 + q * 4 + r) * 4 + hd] = p;
        }
    }
    // phiu = silu(chem @ uW1 + ub1) . uW2 + ub2
    f32x4 uacc[4];
#pragma unroll
    for (int t = 0; t < 4; t++) {
        f32x4 a = (f32x4){0,0,0,0};
        a = __builtin_amdgcn_mfma_f32_16x16x32_bf16(ca0, *(const s16x8*)(&sUW[(t * 16 + ln) * 72 + q * 8]), a, 0, 0, 0);
        a = __builtin_amdgcn_mfma_f32_16x16x32_bf16(ca1, *(const s16x8*)(&sUW[(t * 16 + ln) * 72 + 32 + q * 8]), a, 0, 0, 0);
        uacc[t] = a;
    }
    float up[4] = {0.f, 0.f, 0.f, 0.f};
#pragma unroll
    for (int t = 0; t < 4; t++) {
        float ub = ub1[t * 16 + ln];
        float w2 = uW2[t * 16 + ln];
#pragma unroll
        for (int r = 0; r < 4; r++) up[r] += siluf(uacc[t][r] + ub) * w2;
    }
    float ub2v = ub2[0];
#pragma unroll
    for (int r = 0; r < 4; r++) {
        float s = quadSum(up[r]) + ub2v;
        if (ln == 0) g_phiu[m0 + q * 4 + r] = s;
    }
}

// ---------------- MegaB: pos -> phix, phin + fused scatter ----------------
__global__ __launch_bounds__(256) void k_megaB(
    const float* __restrict__ posW2, const float* __restrict__ posb2,
    const float* __restrict__ xW1, const float* __restrict__ xb1,
    const float* __restrict__ xW2, const float* __restrict__ xb2,
    const float* __restrict__ nW1, const float* __restrict__ nb1,
    const float* __restrict__ nW2, const float* __restrict__ nb2,
    const int* __restrict__ edges, const float* __restrict__ nvecs)
{
    __shared__ u16 sPW[64 * 72], sXW[64 * 72], sNW[64 * 72];
    __shared__ u16 T[4][16 * 72];
    int tid = threadIdx.x;
    stageW(sPW, posW2, tid); stageW(sXW, xW1, tid); stageW(sNW, nW1, tid);
    __syncthreads();
    int lane = tid & 63, q = lane >> 4, ln = lane & 15, w = tid >> 6;
    int m0 = blockIdx.x * 64 + w * 16;
    f32x4 pacc[4];
#pragma unroll
    for (int t = 0; t < 4; t++) pacc[t] = (f32x4){0,0,0,0};
    {
        const u16* ar = g_p1 + (size_t)(m0 + ln) * 64;
#pragma unroll
        for (int k0 = 0; k0 < 2; k0++) {
            s16x8 af = *(const s16x8*)(ar + k0 * 32 + q * 8);
#pragma unroll
            for (int t = 0; t < 4; t++) {
                s16x8 bf = *(const s16x8*)(&sPW[(t * 16 + ln) * 72 + k0 * 32 + q * 8]);
                pacc[t] = __builtin_amdgcn_mfma_f32_16x16x32_bf16(af, bf, pacc[t], 0, 0, 0);
            }
        }
    }
#pragma unroll
    for (int t = 0; t < 4; t++) {
        float pb = posb2[t * 16 + ln];
#pragma unroll
        for (int r = 0; r < 4; r++)
            T[w][(q * 4 + r) * 72 + t * 16 + ln] = f2bu(siluf(pacc[t][r] + pb));
    }
    asm volatile("s_waitcnt lgkmcnt(0)" ::: "memory");
    s16x8 pa0 = *(const s16x8*)(&T[w][ln * 72 + q * 8]);
    s16x8 pa1 = *(const s16x8*)(&T[w][ln * 72 + 32 + q * 8]);
    f32x4 xacc[4], nacc[4];
#pragma unroll
    for (int t = 0; t < 4; t++) {
        f32x4 a = (f32x4){0,0,0,0}, b = (f32x4){0,0,0,0};
        a = __builtin_amdgcn_mfma_f32_16x16x32_bf16(pa0, *(const s16x8*)(&sXW[(t * 16 + ln) * 72 + q * 8]), a, 0, 0, 0);
        a = __builtin_amdgcn_mfma_f32_16x16x32_bf16(pa1, *(const s16x8*)(&sXW[(t * 16 + ln) * 72 + 32 + q * 8]), a, 0, 0, 0);
        b = __builtin_amdgcn_mfma_f32_16x16x32_bf16(pa0, *(const s16x8*)(&sNW[(t * 16 + ln) * 72 + q * 8]), b, 0, 0, 0);
        b = __builtin_amdgcn_mfma_f32_16x16x32_bf16(pa1, *(const s16x8*)(&sNW[(t * 16 + ln) * 72 + 32 + q * 8]), b, 0, 0, 0);
        xacc[t] = a; nacc[t] = b;
    }
    float xp[4] = {0,0,0,0}, np[4] = {0,0,0,0};
#pragma unroll
    for (int t = 0; t < 4; t++) {
        float xb = xb1[t * 16 + ln], nb = nb1[t * 16 + ln];
        float xw = xW2[t * 16 + ln], nw = nW2[t * 16 + ln];
#pragma unroll
        for (int r = 0; r < 4; r++) {
            xp[r] += siluf(xacc[t][r] + xb) * xw;
            np[r] += siluf(nacc[t][r] + nb) * nw;
        }
    }
    float xb2v = xb2[0], nb2v = nb2[0];
#pragma unroll
    for (int r = 0; r < 4; r++) {
        float phix = quadSum(xp[r]) + xb2v;
        float phin = quadSum(np[r]) + nb2v;
        int row = m0 + q * 4 + r;
        float pu = g_phiu[row];
        float tx = pu * phix, tn = pu * phin;
        int rr = edges[row], cc = edges[EE + row];
        if (ln < 3) {
            atomicAdd(&g_xsum[rr * 3 + ln], g_cdl[row * 3 + ln] * tx);
            atomicAdd(&g_nsum[rr * 3 + ln], nvecs[cc * 3 + ln] * tn);
        }
        if (ln == 3) atomicAdd(&g_cnt[rr], 1.f);
    }
}

// ---------------- qp + gate, all heads via blockIdx.y ----------------
__global__ __launch_bounds__(256) void k_qg(const float* __restrict__ Wg, const float* __restrict__ bg)
{
    int hd = blockIdx.y;
    __shared__ u16 sM[64 * 72], sG[64 * 72];
    int tid = threadIdx.x;
    for (int i = tid; i < 4096; i += 256) {
        int k = i >> 6, n = i & 63;
        sM[n * 72 + k] = g_M[hd * 4096 + i];
        sG[n * 72 + k] = f2bu(Wg[(size_t)hd * 4096 + i]);
    }
    __syncthreads();
    int lane = tid & 63, q = lane >> 4, ln = lane & 15, w = tid >> 6;
    int m0 = blockIdx.x * 64 + w * 16;
    f32x4 aM[4], aG[4];
#pragma unroll
    for (int t = 0; t < 4; t++) { aM[t] = (f32x4){0,0,0,0}; aG[t] = (f32x4){0,0,0,0}; }
    const u16* ar = g_z16 + (size_t)(m0 + ln) * 64;
#pragma unroll
    for (int k0 = 0; k0 < 2; k0++) {
        s16x8 af = *(const s16x8*)(ar + k0 * 32 + q * 8);
#pragma unroll
        for (int t = 0; t < 4; t++) {
            s16x8 bm = *(const s16x8*)(&sM[(t * 16 + ln) * 72 + k0 * 32 + q * 8]);
            s16x8 bg_ = *(const s16x8*)(&sG[(t * 16 + ln) * 72 + k0 * 32 + q * 8]);
            aM[t] = __builtin_amdgcn_mfma_f32_16x16x32_bf16(af, bm, aM[t], 0, 0, 0);
            aG[t] = __builtin_amdgcn_mfma_f32_16x16x32_bf16(af, bg_, aG[t], 0, 0, 0);
        }
    }
#pragma unroll
    for (int t = 0; t < 4; t++) {
        float bb = bg[hd * 64 + t * 16 + ln];
#pragma unroll
        for (int r = 0; r < 4; r++) {
            size_t idx = (size_t)(m0 + q * 4 + r) * 64 + t * 16 + ln;
            g_qp4[hd][idx] = f2bu(aM[t][r]);
            g_g4[hd][idx] = f2bu(sigmf(aG[t][r] + bb));
        }
    }
}

// ---------------- attention: MFMA scores, LDS-fed PV (single z gather) ----------------
__global__ __launch_bounds__(256) void k_attn2(const int* __restrict__ klist)
{
    __shared__ __align__(16) float sA[4][4][16];   // [wave][hd][j]
    __shared__ u16 zT[4][16 * 72];                 // [wave][j][d]
    int tid = threadIdx.x;
    int w = tid >> 6, lane = tid & 63, q = lane >> 4, ln = lane & 15;
    int wid = blockIdx.x * 4 + w;
    int nw = gridDim.x * 4;
    u16* zw = zT[w];
    for (int e = wid; e < EE; e += nw) {
        int kv = (lane < 32) ? klist[(size_t)e * 32 + lane] : -1;
        int ij_ln = __shfl(kv, ln);
        s16x8 za0 = {0,0,0,0,0,0,0,0}, za1 = {0,0,0,0,0,0,0,0};
        if (ij_ln >= 0) {
            const u16* zr = g_z16 + (size_t)ij_ln * 64;
            za0 = *(const s16x8*)(zr + q * 8);
            za1 = *(const s16x8*)(zr + 32 + q * 8);
        }
        s16x8 qb0 = {0,0,0,0,0,0,0,0}, qb1 = {0,0,0,0,0,0,0,0};
        if (ln < 4) {
            const u16* qr = &g_qp4[ln][(size_t)e * 64];
            qb0 = *(const s16x8*)(qr + q * 8);
            qb1 = *(const s16x8*)(qr + 32 + q * 8);
        }
        f32x4 sc = (f32x4){0.f, 0.f, 0.f, 0.f};
        sc = __builtin_amdgcn_mfma_f32_16x16x32_bf16(za0, qb0, sc, 0, 0, 0);
        sc = __builtin_amdgcn_mfma_f32_16x16x32_bf16(za1, qb1, sc, 0, 0, 0);
        // park z rows in LDS for PV
        *(s16x8*)(&zw[ln * 72 + q * 8]) = za0;
        *(s16x8*)(&zw[ln * 72 + 32 + q * 8]) = za1;
        // lane holds s[j = q*4+r][hd = ln]
        float s[4];
#pragma unroll
        for (int r = 0; r < 4; r++) {
            int j = q * 4 + r;
            int ij = __shfl(kv, j);
            int jj = __shfl(kv, 16 + j);
            float bvl = (ij >= 0 && ln < 4) ? g_b4[(size_t)jj * 4 + ln] : 0.f;
            s[r] = (ij >= 0) ? (0.125f * sc[r] + bvl) : 0.f;
        }
        float mx = fmaxf(fmaxf(s[0], s[1]), fmaxf(s[2], s[3]));
        mx = fmaxf(mx, __shfl_xor(mx, 16));
        mx = fmaxf(mx, __shfl_xor(mx, 32));
        float ex[4], ps = 0.f;
#pragma unroll
        for (int r = 0; r < 4; r++) { ex[r] = __expf(s[r] - mx); ps += ex[r]; }
        ps += __shfl_xor(ps, 16);
        ps += __shfl_xor(ps, 32);
        float inv = 1.f / ps;
        if (ln < 4)
            *(f32x4*)&sA[w][ln][q * 4] = (f32x4){ex[0] * inv, ex[1] * inv, ex[2] * inv, ex[3] * inv};
        asm volatile("s_waitcnt lgkmcnt(0)" ::: "memory");
        // PV from LDS: lane = feature d
        float t0 = 0.f, t1 = 0.f, t2 = 0.f, t3 = 0.f;
#pragma unroll
        for (int j4 = 0; j4 < 4; j4++) {
            f32x4 a0 = *(const f32x4*)&sA[w][0][j4 * 4];
            f32x4 a1 = *(const f32x4*)&sA[w][1][j4 * 4];
            f32x4 a2 = *(const f32x4*)&sA[w][2][j4 * 4];
            f32x4 a3 = *(const f32x4*)&sA[w][3][j4 * 4];
#pragma unroll
            for (int r = 0; r < 4; r++) {
                float zz = us2f(zw[(j4 * 4 + r) * 72 + lane]);
                t0 += a0[r] * zz; t1 += a1[r] * zz; t2 += a2[r] * zz; t3 += a3[r] * zz;
            }
        }
        size_t ob = (size_t)e * 64 + lane;
        g_t4[0][ob] = f2bu(t0);
        g_t4[1][ob] = f2bu(t1);
        g_t4[2][ob] = f2bu(t2);
        g_t4[3][ob] = f2bu(t3);
    }
}

// ---------------- u = (t @ Wv) * g ; msum += u @ out_W ----------------
__global__ __launch_bounds__(256) void k_us(
    const float* __restrict__ Wv, const float* __restrict__ oW, const int* __restrict__ edges)
{
    int hd = blockIdx.y;
    __shared__ u16 sV[64 * 72], sO[64 * 72], sU[64 * 72];
    int tid = threadIdx.x;
    for (int i = tid; i < 4096; i += 256) {
        int k = i >> 6, n = i & 63;
        sV[n * 72 + k] = f2bu(Wv[(size_t)hd * 4096 + i]);
        sO[n * 72 + k] = f2bu(oW[(size_t)hd * 4096 + i]);
    }
    __syncthreads();
    int lane = tid & 63, q = lane >> 4, ln = lane & 15, w = tid >> 6;
    int m0 = blockIdx.x * 64 + w * 16;
    f32x4 acc[4];
#pragma unroll
    for (int t = 0; t < 4; t++) acc[t] = (f32x4){0,0,0,0};
    const u16* ar = &g_t4[hd][(size_t)(m0 + ln) * 64];
#pragma unroll
    for (int k0 = 0; k0 < 2; k0++) {
        s16x8 af = *(const s16x8*)(ar + k0 * 32 + q * 8);
#pragma unroll
        for (int t = 0; t < 4; t++) {
            s16x8 bf = *(const s16x8*)(&sV[(t * 16 + ln) * 72 + k0 * 32 + q * 8]);
            acc[t] = __builtin_amdgcn_mfma_f32_16x16x32_bf16(af, bf, acc[t], 0, 0, 0);
        }
    }
#pragma unroll
    for (int t = 0; t < 4; t++)
#pragma unroll
        for (int r = 0; r < 4; r++) {
            size_t row = m0 + q * 4 + r;
            float u = acc[t][r] * us2f(g_g4[hd][row * 64 + t * 16 + ln]);
            sU[(w * 16 + q * 4 + r) * 72 + t * 16 + ln] = f2bu(u);
        }
    __syncthreads();
    f32x4 a2[4];
#pragma unroll
    for (int t = 0; t < 4; t++) a2[t] = (f32x4){0,0,0,0};
#pragma unroll
    for (int k0 = 0; k0 < 2; k0++) {
        s16x8 af = *(const s16x8*)(&sU[(w * 16 + ln) * 72 + k0 * 32 + q * 8]);
#pragma unroll
        for (int t = 0; t < 4; t++) {
            s16x8 bf = *(const s16x8*)(&sO[(t * 16 + ln) * 72 + k0 * 32 + q * 8]);
            a2[t] = __builtin_amdgcn_mfma_f32_16x16x32_bf16(af, bf, a2[t], 0, 0, 0);
        }
    }
#pragma unroll
    for (int r = 0; r < 4; r++) {
        int dst = edges[m0 + q * 4 + r] * 64;
#pragma unroll
        for (int t = 0; t < 4; t++) atomicAdd(&g_msum[dst + t * 16 + ln], a2[t][r]);
    }
}

// ---------------- node finalize ----------------
__global__ __launch_bounds__(256) void k_node(
    const float* __restrict__ h, const float* __restrict__ na,
    const float* __restrict__ coord, const float* __restrict__ nvecs,
    const float* __restrict__ icoord, const float* __restrict__ invecs,
    const float* __restrict__ ob,
    const float* __restrict__ W1, const float* __restrict__ b1,
    const float* __restrict__ W2, const float* __restrict__ b2,
    float* __restrict__ out)
{
    __shared__ u16 sW1[192 * 64], sW2[4096];
    __shared__ float sb1[64], sb2[64];
    int tid = threadIdx.x;
    for (int i = tid; i < 192 * 64; i += 256) sW1[i] = f2bu(W1[i]);
    for (int i = tid; i < 4096; i += 256) sW2[i] = f2bu(W2[i]);
    if (tid < 64) { sb1[tid] = b1[tid]; sb2[tid] = b2[tid]; }
    __syncthreads();
    size_t coff = (size_t)NN * 64;
    size_t noff = coff + (size_t)NN * 3;
    int lane = tid & 63;
    int wid = blockIdx.x * 4 + (tid >> 6);
    int nw = gridDim.x * 4;
    for (int n = wid; n < NN; n += nw) {
        float craw = g_cnt[n];
        float rinv = 1.f / fmaxf(craw, 1.f);
        float hl = h[(size_t)n * 64 + lane];
        float al = na[(size_t)n * 64 + lane];
        float obv = (craw > 0.f) ? ob[lane] : 0.f;
        float ml = g_msum[n * 64 + lane] * rinv + obv;
        float acc = sb1[lane];
        for (int i = 0; i < 64; i++) acc += __shfl(hl, i) * us2f(sW1[i * 64 + lane]);
        for (int i = 0; i < 64; i++) acc += __shfl(al, i) * us2f(sW1[(64 + i) * 64 + lane]);
        for (int i = 0; i < 64; i++) acc += __shfl(ml, i) * us2f(sW1[(128 + i) * 64 + lane]);
        float t = siluf(acc);
        float a2 = sb2[lane];
        for (int i = 0; i < 64; i++) a2 += __shfl(t, i) * us2f(sW2[i * 64 + lane]);
        out[(size_t)n * 64 + lane] = 0.2f * hl + 0.8f * a2;
        if (lane < 3) {
            out[coff + n * 3 + lane] = 0.2f * icoord[n * 3 + lane] + 0.8f * coord[n * 3 + lane]
                                       + g_xsum[n * 3 + lane] * rinv;
        }
        float nl = (lane < 3)
            ? (0.2f * invecs[n * 3 + lane] + 0.8f * nvecs[n * 3 + lane] + g_nsum[n * 3 + lane] * rinv)
            : 0.f;
        float nn = sqrtf(waveSum(nl * nl)) + 1e-8f;
        if (lane < 3) out[noff + n * 3 + lane] = nl / nn;
    }
}

extern "C" void kernel_launch(void* const* d_in, const int* in_sizes, int n_in,
                              void* d_out, int out_size, void* d_ws, size_t ws_size,
                              hipStream_t stream)
{
    const int* edges = (const int*)d_in[43];
    const int* klist = (const int*)d_in[44];
    auto F = [&](int i) { return (const float*)d_in[i]; };

    k_prep<<<512, 256, 0, stream>>>(F(19), F(20));
    k_geom<<<1024, 256, 0, stream>>>(F(1), F(2), edges, F(11), F(12));
    k_chem1<<<3125, 256, 0, stream>>>(F(0), F(4), F(3), edges, F(7), F(8));
    k_megaA<<<3125, 256, 0, stream>>>(F(9), F(10), F(13), F(14), F(15), F(16),
                                      F(17), F(18), F(22), F(27), F(28), F(29), F(30));
    k_megaB<<<3125, 256, 0, stream>>>(F(13), F(14), F(31), F(32), F(33), F(34),
                                      F(35), F(36), F(37), F(38), edges, F(2));
    k_qg<<<dim3(3125, 4), 256, 0, stream>>>(F(23), F(24));
    k_attn2<<<2048, 256, 0, stream>>>(klist);
    k_us<<<dim3(3125, 4), 256, 0, stream>>>(F(21), F(25), edges);
    k_node<<<640, 256, 0, stream>>>(F(0), F(4), F(1), F(2), F(5), F(6), F(26),
                                    F(39), F(40), F(41), F(42), (float*)d_out);
}

// Round 9
// 997.184 us; speedup vs baseline: 16.0170x; 1.2560x over previous
//
#include <hip/hip_runtime.h>

typedef unsigned short u16;
typedef unsigned int u32;
typedef __attribute__((ext_vector_type(8))) short s16x8;
typedef __attribute__((ext_vector_type(4))) float f32x4;

#define NN 10000
#define EE 200000
#define ES ((size_t)EE * 64)

#define DEVI __device__ __forceinline__

DEVI float us2f(u16 u) {
    union { u32 i; float f; } v; v.i = ((u32)u) << 16; return v.f;
}
DEVI u16 f2bu(float f) {
    union { float f; u32 i; } v; v.f = f;
    u32 x = v.i;
    return (u16)((x + 0x7fffu + ((x >> 16) & 1u)) >> 16);
}
DEVI float siluf(float x) { return x / (1.f + __expf(-x)); }
DEVI float sigmf(float x) { return 1.f / (1.f + __expf(-x)); }
DEVI float waveSum(float v) {
#pragma unroll
    for (int o = 32; o; o >>= 1) v += __shfl_xor(v, o);
    return v;
}
DEVI float quadSum(float v) {
#pragma unroll
    for (int o = 1; o < 16; o <<= 1) v += __shfl_xor(v, o);
    return v;
}

// ---- module-owned scratch ----
__device__ u16 g_t1[ES];          // chem layer1 out
__device__ u16 g_p1[ES];          // pos layer1 out
__device__ u16 g_z16[ES];
__device__ u16 g_qp4[4][ES];      // per-head q-projected
__device__ u16 g_t4[4][ES];       // per-head aggregated z
__device__ u16 g_M[4 * 4096];     // Wq Wk^T per head, [hd][k][n]
__device__ float g_b4[(size_t)EE * 4];   // [e][hd]
__device__ float g_phiu[EE];
__device__ float g_cdl[EE * 3];
__device__ float g_msum[NN * 64];
__device__ float g_xsum[NN * 3];
__device__ float g_nsum[NN * 3];
__device__ float g_cnt[NN];

// ---------------- M precompute + accumulator zeroing (merged) ----------------
__global__ __launch_bounds__(256) void k_prep(const float* __restrict__ Wq, const float* __restrict__ Wk)
{
    int t = blockIdx.x * 256 + threadIdx.x;
    if (t < 16384) {
        int hd = t >> 12, rem = t & 4095, k = rem >> 6, n = rem & 63;
        const float* wq = Wq + (size_t)hd * 4096 + k * 64;
        const float* wk = Wk + (size_t)hd * 4096 + n * 64;
        float acc = 0.f;
        for (int d = 0; d < 64; d++) acc += wq[d] * wk[d];
        g_M[t] = f2bu(acc);
    }
    int nt = gridDim.x * 256;
    for (int i = t; i < NN * 64; i += nt) g_msum[i] = 0.f;
    for (int i = t; i < NN * 3; i += nt) { g_xsum[i] = 0.f; g_nsum[i] = 0.f; }
    for (int i = t; i < NN; i += nt) g_cnt[i] = 0.f;
}

// ---------------- geometry + pos layer1 ----------------
__global__ __launch_bounds__(256) void k_geom(
    const float* __restrict__ coord, const float* __restrict__ nvecs,
    const int* __restrict__ edges, const float* __restrict__ pW1, const float* __restrict__ pb1)
{
    int lane = threadIdx.x & 63;
    int wid = blockIdx.x * 4 + (threadIdx.x >> 6);
    int nw = gridDim.x * 4;
    float w0 = pW1[lane], w1 = pW1[64 + lane], b0 = pb1[lane];
    for (int e = wid; e < EE; e += nw) {
        int r = edges[e], c = edges[EE + e];
        float dl = (lane < 3) ? (coord[r * 3 + lane] - coord[c * 3 + lane]) : 0.f;
        float radial = waveSum(dl * dl);
        float nvr = (lane < 3) ? nvecs[r * 3 + lane] : 0.f;
        float nvc = (lane < 3) ? nvecs[c * 3 + lane] : 0.f;
        float nprod = waveSum(nvr * nvc);
        if (lane < 3) g_cdl[e * 3 + lane] = dl / (sqrtf(radial) + 1e-8f);
        g_p1[(size_t)e * 64 + lane] = f2bu(siluf(b0 + nprod * w0 + radial * w1));
    }
}

// ---------------- chem layer1: gathered-A GEMM, K=288 ----------------
__global__ __launch_bounds__(256) void k_chem1(
    const float* __restrict__ h, const float* __restrict__ na, const float* __restrict__ ea,
    const int* __restrict__ edges, const float* __restrict__ W1, const float* __restrict__ b1)
{
    __shared__ u16 sBT[64 * 296];
    int tid = threadIdx.x;
    for (int i = tid; i < 64 * 296; i += 256) {
        int n = i / 296, k = i - n * 296;
        sBT[i] = (k < 272) ? f2bu(W1[k * 64 + n]) : (u16)0;
    }
    __syncthreads();
    int lane = tid & 63, q = lane >> 4, ln = lane & 15, w = tid >> 6;
    int m0 = blockIdx.x * 64 + w * 16;
    int e = m0 + ln;
    int r_ = edges[e], c_ = edges[EE + e];
    f32x4 acc[4];
#pragma unroll
    for (int t = 0; t < 4; t++) acc[t] = (f32x4){0.f, 0.f, 0.f, 0.f};
#pragma unroll
    for (int k0 = 0; k0 < 9; k0++) {
        int k = k0 * 32 + q * 8;
        s16x8 af = {0, 0, 0, 0, 0, 0, 0, 0};
        const float* p = nullptr;
        if (k < 64)       p = h  + (size_t)r_ * 64 + k;
        else if (k < 128) p = h  + (size_t)c_ * 64 + (k - 64);
        else if (k < 192) p = na + (size_t)r_ * 64 + (k - 128);
        else if (k < 256) p = na + (size_t)c_ * 64 + (k - 192);
        else if (k < 272) p = ea + (size_t)e * 16 + (k - 256);
        if (p) {
            float4 f0 = *(const float4*)(p);
            float4 f1 = *(const float4*)(p + 4);
            af[0] = (short)f2bu(f0.x); af[1] = (short)f2bu(f0.y);
            af[2] = (short)f2bu(f0.z); af[3] = (short)f2bu(f0.w);
            af[4] = (short)f2bu(f1.x); af[5] = (short)f2bu(f1.y);
            af[6] = (short)f2bu(f1.z); af[7] = (short)f2bu(f1.w);
        }
#pragma unroll
        for (int t = 0; t < 4; t++) {
            s16x8 bf = *(const s16x8*)(&sBT[(t * 16 + ln) * 296 + k0 * 32 + q * 8]);
            acc[t] = __builtin_amdgcn_mfma_f32_16x16x32_bf16(af, bf, acc[t], 0, 0, 0);
        }
    }
#pragma unroll
    for (int t = 0; t < 4; t++) {
        float bv = b1[t * 16 + ln];
#pragma unroll
        for (int r = 0; r < 4; r++)
            g_t1[(size_t)(m0 + q * 4 + r) * 64 + t * 16 + ln] = f2bu(siluf(acc[t][r] + bv));
    }
}

// helper: stage a 64x64 f32 weight as bf16 [n][k] stride-72 tile
DEVI void stageW(u16* dst, const float* src, int tid) {
    for (int i = tid; i < 4096; i += 256) {
        int k = i >> 6, n = i & 63;
        dst[n * 72 + k] = f2bu(src[i]);
    }
}

// ---------------- MegaA: pos, chem -> z, b4, phiu ----------------
__global__ __launch_bounds__(256) void k_megaA(
    const float* __restrict__ chW2, const float* __restrict__ chb2,
    const float* __restrict__ posW2, const float* __restrict__ posb2,
    const float* __restrict__ shW, const float* __restrict__ shb,
    const float* __restrict__ attW, const float* __restrict__ attb,
    const float* __restrict__ Wb,
    const float* __restrict__ uW1, const float* __restrict__ ub1,
    const float* __restrict__ uW2, const float* __restrict__ ub2)
{
    __shared__ u16 sCH[64 * 72], sPW[64 * 72], sSH[64 * 72], sUW[64 * 72];
    __shared__ u16 T[4][16 * 72];
    __shared__ float sWB[256], sATT[64];
    int tid = threadIdx.x;
    stageW(sCH, chW2, tid); stageW(sPW, posW2, tid);
    stageW(sSH, shW, tid);  stageW(sUW, uW1, tid);
    sWB[tid] = Wb[tid];
    if (tid < 64) sATT[tid] = attW[tid];
    __syncthreads();
    int lane = tid & 63, q = lane >> 4, ln = lane & 15, w = tid >> 6;
    int m0 = blockIdx.x * 64 + w * 16;
    f32x4 pacc[4];
#pragma unroll
    for (int t = 0; t < 4; t++) pacc[t] = (f32x4){0,0,0,0};
    {
        const u16* ar = g_p1 + (size_t)(m0 + ln) * 64;
#pragma unroll
        for (int k0 = 0; k0 < 2; k0++) {
            s16x8 af = *(const s16x8*)(ar + k0 * 32 + q * 8);
#pragma unroll
            for (int t = 0; t < 4; t++) {
                s16x8 bf = *(const s16x8*)(&sPW[(t * 16 + ln) * 72 + k0 * 32 + q * 8]);
                pacc[t] = __builtin_amdgcn_mfma_f32_16x16x32_bf16(af, bf, pacc[t], 0, 0, 0);
            }
        }
    }
    float posD[4][4];
#pragma unroll
    for (int t = 0; t < 4; t++) {
        float pb = posb2[t * 16 + ln];
#pragma unroll
        for (int r = 0; r < 4; r++) posD[t][r] = siluf(pacc[t][r] + pb);
    }
    f32x4 cacc[4];
#pragma unroll
    for (int t = 0; t < 4; t++) cacc[t] = (f32x4){0,0,0,0};
    {
        const u16* ar = g_t1 + (size_t)(m0 + ln) * 64;
#pragma unroll
        for (int k0 = 0; k0 < 2; k0++) {
            s16x8 af = *(const s16x8*)(ar + k0 * 32 + q * 8);
#pragma unroll
            for (int t = 0; t < 4; t++) {
                s16x8 bf = *(const s16x8*)(&sCH[(t * 16 + ln) * 72 + k0 * 32 + q * 8]);
                cacc[t] = __builtin_amdgcn_mfma_f32_16x16x32_bf16(af, bf, cacc[t], 0, 0, 0);
            }
        }
    }
#pragma unroll
    for (int t = 0; t < 4; t++) {
        float cb = chb2[t * 16 + ln];
#pragma unroll
        for (int r = 0; r < 4; r++)
            T[w][(q * 4 + r) * 72 + t * 16 + ln] = f2bu(siluf(cacc[t][r] + cb));
    }
    asm volatile("s_waitcnt lgkmcnt(0)" ::: "memory");
    s16x8 ca0 = *(const s16x8*)(&T[w][ln * 72 + q * 8]);
    s16x8 ca1 = *(const s16x8*)(&T[w][ln * 72 + 32 + q * 8]);
    f32x4 sacc[4];
#pragma unroll
    for (int t = 0; t < 4; t++) {
        f32x4 a = (f32x4){0,0,0,0};
        a = __builtin_amdgcn_mfma_f32_16x16x32_bf16(ca0, *(const s16x8*)(&sSH[(t * 16 + ln) * 72 + q * 8]), a, 0, 0, 0);
        a = __builtin_amdgcn_mfma_f32_16x16x32_bf16(ca1, *(const s16x8*)(&sSH[(t * 16 + ln) * 72 + 32 + q * 8]), a, 0, 0, 0);
        sacc[t] = a;
    }
    float zv[4][4];
    float part[4] = {0.f, 0.f, 0.f, 0.f};
#pragma unroll
    for (int t = 0; t < 4; t++) {
        float sb = shb[t * 16 + ln];
        float aw = sATT[t * 16 + ln];
#pragma unroll
        for (int r = 0; r < 4; r++) {
            float o = siluf(sacc[t][r] + sb) * posD[t][r];
            zv[t][r] = o;
            part[r] += o * aw;
        }
    }
    float ab = attb[0];
#pragma unroll
    for (int r = 0; r < 4; r++) {
        float sg = sigmf(quadSum(part[r]) + ab);
        size_t row = m0 + q * 4 + r;
#pragma unroll
        for (int t = 0; t < 4; t++) {
            float z = zv[t][r] * sg;
            zv[t][r] = z;
            g_z16[row * 64 + t * 16 + ln] = f2bu(z);
        }
    }
#pragma unroll
    for (int hd = 0; hd < 4; hd++) {
#pragma unroll
        for (int r = 0; r < 4; r++) {
            float p = 0.f;
#pragma unroll
            for (int t = 0; t < 4; t++) p += zv[t][r] * sWB[hd * 64 + t * 16 + ln];
            p = quadSum(p);
            if (ln == hd) g_b4[(size_t)(m0 + q * 4 + r) * 4 + hd] = p;
        }
    }
    f32x4 uacc[4];
#pragma unroll
    for (int t = 0; t < 4; t++) {
        f32x4 a = (f32x4){0,0,0,0};
        a = __builtin_amdgcn_mfma_f32_16x16x32_bf16(ca0, *(const s16x8*)(&sUW[(t * 16 + ln) * 72 + q * 8]), a, 0, 0, 0);
        a = __builtin_amdgcn_mfma_f32_16x16x32_bf16(ca1, *(const s16x8*)(&sUW[(t * 16 + ln) * 72 + 32 + q * 8]), a, 0, 0, 0);
        uacc[t] = a;
    }
    float up[4] = {0.f, 0.f, 0.f, 0.f};
#pragma unroll
    for (int t = 0; t < 4; t++) {
        float ub = ub1[t * 16 + ln];
        float w2 = uW2[t * 16 + ln];
#pragma unroll
        for (int r = 0; r < 4; r++) up[r] += siluf(uacc[t][r] + ub) * w2;
    }
    float ub2v = ub2[0];
#pragma unroll
    for (int r = 0; r < 4; r++) {
        float s = quadSum(up[r]) + ub2v;
        if (ln == 0) g_phiu[m0 + q * 4 + r] = s;
    }
}

// ---------------- MegaB: pos -> phix, phin + fused scatter ----------------
__global__ __launch_bounds__(256) void k_megaB(
    const float* __restrict__ posW2, const float* __restrict__ posb2,
    const float* __restrict__ xW1, const float* __restrict__ xb1,
    const float* __restrict__ xW2, const float* __restrict__ xb2,
    const float* __restrict__ nW1, const float* __restrict__ nb1,
    const float* __restrict__ nW2, const float* __restrict__ nb2,
    const int* __restrict__ edges, const float* __restrict__ nvecs)
{
    __shared__ u16 sPW[64 * 72], sXW[64 * 72], sNW[64 * 72];
    __shared__ u16 T[4][16 * 72];
    int tid = threadIdx.x;
    stageW(sPW, posW2, tid); stageW(sXW, xW1, tid); stageW(sNW, nW1, tid);
    __syncthreads();
    int lane = tid & 63, q = lane >> 4, ln = lane & 15, w = tid >> 6;
    int m0 = blockIdx.x * 64 + w * 16;
    f32x4 pacc[4];
#pragma unroll
    for (int t = 0; t < 4; t++) pacc[t] = (f32x4){0,0,0,0};
    {
        const u16* ar = g_p1 + (size_t)(m0 + ln) * 64;
#pragma unroll
        for (int k0 = 0; k0 < 2; k0++) {
            s16x8 af = *(const s16x8*)(ar + k0 * 32 + q * 8);
#pragma unroll
            for (int t = 0; t < 4; t++) {
                s16x8 bf = *(const s16x8*)(&sPW[(t * 16 + ln) * 72 + k0 * 32 + q * 8]);
                pacc[t] = __builtin_amdgcn_mfma_f32_16x16x32_bf16(af, bf, pacc[t], 0, 0, 0);
            }
        }
    }
#pragma unroll
    for (int t = 0; t < 4; t++) {
        float pb = posb2[t * 16 + ln];
#pragma unroll
        for (int r = 0; r < 4; r++)
            T[w][(q * 4 + r) * 72 + t * 16 + ln] = f2bu(siluf(pacc[t][r] + pb));
    }
    asm volatile("s_waitcnt lgkmcnt(0)" ::: "memory");
    s16x8 pa0 = *(const s16x8*)(&T[w][ln * 72 + q * 8]);
    s16x8 pa1 = *(const s16x8*)(&T[w][ln * 72 + 32 + q * 8]);
    f32x4 xacc[4], nacc[4];
#pragma unroll
    for (int t = 0; t < 4; t++) {
        f32x4 a = (f32x4){0,0,0,0}, b = (f32x4){0,0,0,0};
        a = __builtin_amdgcn_mfma_f32_16x16x32_bf16(pa0, *(const s16x8*)(&sXW[(t * 16 + ln) * 72 + q * 8]), a, 0, 0, 0);
        a = __builtin_amdgcn_mfma_f32_16x16x32_bf16(pa1, *(const s16x8*)(&sXW[(t * 16 + ln) * 72 + 32 + q * 8]), a, 0, 0, 0);
        b = __builtin_amdgcn_mfma_f32_16x16x32_bf16(pa0, *(const s16x8*)(&sNW[(t * 16 + ln) * 72 + q * 8]), b, 0, 0, 0);
        b = __builtin_amdgcn_mfma_f32_16x16x32_bf16(pa1, *(const s16x8*)(&sNW[(t * 16 + ln) * 72 + 32 + q * 8]), b, 0, 0, 0);
        xacc[t] = a; nacc[t] = b;
    }
    float xp[4] = {0,0,0,0}, np[4] = {0,0,0,0};
#pragma unroll
    for (int t = 0; t < 4; t++) {
        float xb = xb1[t * 16 + ln], nb = nb1[t * 16 + ln];
        float xw = xW2[t * 16 + ln], nw = nW2[t * 16 + ln];
#pragma unroll
        for (int r = 0; r < 4; r++) {
            xp[r] += siluf(xacc[t][r] + xb) * xw;
            np[r] += siluf(nacc[t][r] + nb) * nw;
        }
    }
    float xb2v = xb2[0], nb2v = nb2[0];
#pragma unroll
    for (int r = 0; r < 4; r++) {
        float phix = quadSum(xp[r]) + xb2v;
        float phin = quadSum(np[r]) + nb2v;
        int row = m0 + q * 4 + r;
        float pu = g_phiu[row];
        float tx = pu * phix, tn = pu * phin;
        int rr = edges[row], cc = edges[EE + row];
        if (ln < 3) {
            atomicAdd(&g_xsum[rr * 3 + ln], g_cdl[row * 3 + ln] * tx);
            atomicAdd(&g_nsum[rr * 3 + ln], nvecs[cc * 3 + ln] * tn);
        }
        if (ln == 3) atomicAdd(&g_cnt[rr], 1.f);
    }
}

// ---------------- qp per head (gate moved into k_us) ----------------
__global__ __launch_bounds__(256) void k_q()
{
    int hd = blockIdx.y;
    __shared__ u16 sM[64 * 72];
    int tid = threadIdx.x;
    for (int i = tid; i < 4096; i += 256) {
        int k = i >> 6, n = i & 63;
        sM[n * 72 + k] = g_M[hd * 4096 + i];
    }
    __syncthreads();
    int lane = tid & 63, q = lane >> 4, ln = lane & 15, w = tid >> 6;
    int m0 = blockIdx.x * 64 + w * 16;
    f32x4 aM[4];
#pragma unroll
    for (int t = 0; t < 4; t++) aM[t] = (f32x4){0,0,0,0};
    const u16* ar = g_z16 + (size_t)(m0 + ln) * 64;
#pragma unroll
    for (int k0 = 0; k0 < 2; k0++) {
        s16x8 af = *(const s16x8*)(ar + k0 * 32 + q * 8);
#pragma unroll
        for (int t = 0; t < 4; t++) {
            s16x8 bm = *(const s16x8*)(&sM[(t * 16 + ln) * 72 + k0 * 32 + q * 8]);
            aM[t] = __builtin_amdgcn_mfma_f32_16x16x32_bf16(af, bm, aM[t], 0, 0, 0);
        }
    }
#pragma unroll
    for (int t = 0; t < 4; t++)
#pragma unroll
        for (int r = 0; r < 4; r++)
            g_qp4[hd][(size_t)(m0 + q * 4 + r) * 64 + t * 16 + ln] = f2bu(aM[t][r]);
}

// ---------------- attention: MFMA scores, LDS-fed PV (single z gather) ----------------
__global__ __launch_bounds__(256) void k_attn2(const int* __restrict__ klist)
{
    __shared__ __align__(16) float sA[4][4][16];   // [wave][hd][j]
    __shared__ u16 zT[4][16 * 72];                 // [wave][j][d]
    int tid = threadIdx.x;
    int w = tid >> 6, lane = tid & 63, q = lane >> 4, ln = lane & 15;
    int wid = blockIdx.x * 4 + w;
    int nw = gridDim.x * 4;
    u16* zw = zT[w];
    for (int e = wid; e < EE; e += nw) {
        int kv = (lane < 32) ? klist[(size_t)e * 32 + lane] : -1;
        int ij_ln = __shfl(kv, ln);
        s16x8 za0 = {0,0,0,0,0,0,0,0}, za1 = {0,0,0,0,0,0,0,0};
        if (ij_ln >= 0) {
            const u16* zr = g_z16 + (size_t)ij_ln * 64;
            za0 = *(const s16x8*)(zr + q * 8);
            za1 = *(const s16x8*)(zr + 32 + q * 8);
        }
        s16x8 qb0 = {0,0,0,0,0,0,0,0}, qb1 = {0,0,0,0,0,0,0,0};
        if (ln < 4) {
            const u16* qr = &g_qp4[ln][(size_t)e * 64];
            qb0 = *(const s16x8*)(qr + q * 8);
            qb1 = *(const s16x8*)(qr + 32 + q * 8);
        }
        f32x4 sc = (f32x4){0.f, 0.f, 0.f, 0.f};
        sc = __builtin_amdgcn_mfma_f32_16x16x32_bf16(za0, qb0, sc, 0, 0, 0);
        sc = __builtin_amdgcn_mfma_f32_16x16x32_bf16(za1, qb1, sc, 0, 0, 0);
        *(s16x8*)(&zw[ln * 72 + q * 8]) = za0;
        *(s16x8*)(&zw[ln * 72 + 32 + q * 8]) = za1;
        float s[4];
#pragma unroll
        for (int r = 0; r < 4; r++) {
            int j = q * 4 + r;
            int ij = __shfl(kv, j);
            int jj = __shfl(kv, 16 + j);
            float bvl = (ij >= 0 && ln < 4) ? g_b4[(size_t)jj * 4 + ln] : 0.f;
            s[r] = (ij >= 0) ? (0.125f * sc[r] + bvl) : 0.f;
        }
        float mx = fmaxf(fmaxf(s[0], s[1]), fmaxf(s[2], s[3]));
        mx = fmaxf(mx, __shfl_xor(mx, 16));
        mx = fmaxf(mx, __shfl_xor(mx, 32));
        float ex[4], ps = 0.f;
#pragma unroll
        for (int r = 0; r < 4; r++) { ex[r] = __expf(s[r] - mx); ps += ex[r]; }
        ps += __shfl_xor(ps, 16);
        ps += __shfl_xor(ps, 32);
        float inv = 1.f / ps;
        if (ln < 4)
            *(f32x4*)&sA[w][ln][q * 4] = (f32x4){ex[0] * inv, ex[1] * inv, ex[2] * inv, ex[3] * inv};
        asm volatile("s_waitcnt lgkmcnt(0)" ::: "memory");
        float t0 = 0.f, t1 = 0.f, t2 = 0.f, t3 = 0.f;
#pragma unroll
        for (int j4 = 0; j4 < 4; j4++) {
            f32x4 a0 = *(const f32x4*)&sA[w][0][j4 * 4];
            f32x4 a1 = *(const f32x4*)&sA[w][1][j4 * 4];
            f32x4 a2 = *(const f32x4*)&sA[w][2][j4 * 4];
            f32x4 a3 = *(const f32x4*)&sA[w][3][j4 * 4];
#pragma unroll
            for (int r = 0; r < 4; r++) {
                float zz = us2f(zw[(j4 * 4 + r) * 72 + lane]);
                t0 += a0[r] * zz; t1 += a1[r] * zz; t2 += a2[r] * zz; t3 += a3[r] * zz;
            }
        }
        size_t ob = (size_t)e * 64 + lane;
        g_t4[0][ob] = f2bu(t0);
        g_t4[1][ob] = f2bu(t1);
        g_t4[2][ob] = f2bu(t2);
        g_t4[3][ob] = f2bu(t3);
    }
}

// ---------------- fused heads: u=(t@Wv)*sigm(z@Wg+bg); m=Σ_hd u@oW_hd; one atomic pass ----------------
__global__ __launch_bounds__(256) void k_us(
    const float* __restrict__ Wv, const float* __restrict__ Wg, const float* __restrict__ bg,
    const float* __restrict__ oW, const int* __restrict__ edges)
{
    __shared__ u16 sV[64 * 72], sO[64 * 72], sG[64 * 72];
    __shared__ u16 sU[4][16 * 72];
    int tid = threadIdx.x;
    int lane = tid & 63, q = lane >> 4, ln = lane & 15, w = tid >> 6;
    int m0 = blockIdx.x * 64 + w * 16;
    // z rows for the gate GEMM (constant across heads; L1-resident)
    const u16* zr = g_z16 + (size_t)(m0 + ln) * 64;
    s16x8 za[2];
    za[0] = *(const s16x8*)(zr + q * 8);
    za[1] = *(const s16x8*)(zr + 32 + q * 8);
    f32x4 macc[4];
#pragma unroll
    for (int t = 0; t < 4; t++) macc[t] = (f32x4){0,0,0,0};
    for (int hd = 0; hd < 4; hd++) {
        if (hd) __syncthreads();
        stageW(sV, Wv + (size_t)hd * 4096, tid);
        stageW(sO, oW + (size_t)hd * 4096, tid);
        stageW(sG, Wg + (size_t)hd * 4096, tid);
        __syncthreads();
        f32x4 vacc[4], gacc[4];
#pragma unroll
        for (int t = 0; t < 4; t++) { vacc[t] = (f32x4){0,0,0,0}; gacc[t] = (f32x4){0,0,0,0}; }
        const u16* ar = &g_t4[hd][(size_t)(m0 + ln) * 64];
#pragma unroll
        for (int k0 = 0; k0 < 2; k0++) {
            s16x8 af = *(const s16x8*)(ar + k0 * 32 + q * 8);
#pragma unroll
            for (int t = 0; t < 4; t++) {
                vacc[t] = __builtin_amdgcn_mfma_f32_16x16x32_bf16(
                    af, *(const s16x8*)(&sV[(t * 16 + ln) * 72 + k0 * 32 + q * 8]), vacc[t], 0, 0, 0);
                gacc[t] = __builtin_amdgcn_mfma_f32_16x16x32_bf16(
                    za[k0], *(const s16x8*)(&sG[(t * 16 + ln) * 72 + k0 * 32 + q * 8]), gacc[t], 0, 0, 0);
            }
        }
#pragma unroll
        for (int t = 0; t < 4; t++) {
            float bb = bg[hd * 64 + t * 16 + ln];
#pragma unroll
            for (int r = 0; r < 4; r++) {
                float u = vacc[t][r] * sigmf(gacc[t][r] + bb);
                sU[w][(q * 4 + r) * 72 + t * 16 + ln] = f2bu(u);
            }
        }
        asm volatile("s_waitcnt lgkmcnt(0)" ::: "memory");
#pragma unroll
        for (int k0 = 0; k0 < 2; k0++) {
            s16x8 af = *(const s16x8*)(&sU[w][ln * 72 + k0 * 32 + q * 8]);
#pragma unroll
            for (int t = 0; t < 4; t++) {
                macc[t] = __builtin_amdgcn_mfma_f32_16x16x32_bf16(
                    af, *(const s16x8*)(&sO[(t * 16 + ln) * 72 + k0 * 32 + q * 8]), macc[t], 0, 0, 0);
            }
        }
    }
#pragma unroll
    for (int r = 0; r < 4; r++) {
        int dst = edges[m0 + q * 4 + r] * 64;
#pragma unroll
        for (int t = 0; t < 4; t++) atomicAdd(&g_msum[dst + t * 16 + ln], macc[t][r]);
    }
}

// ---------------- node finalize ----------------
__global__ __launch_bounds__(256) void k_node(
    const float* __restrict__ h, const float* __restrict__ na,
    const float* __restrict__ coord, const float* __restrict__ nvecs,
    const float* __restrict__ icoord, const float* __restrict__ invecs,
    const float* __restrict__ ob,
    const float* __restrict__ W1, const float* __restrict__ b1,
    const float* __restrict__ W2, const float* __restrict__ b2,
    float* __restrict__ out)
{
    __shared__ u16 sW1[192 * 64], sW2[4096];
    __shared__ float sb1[64], sb2[64];
    int tid = threadIdx.x;
    for (int i = tid; i < 192 * 64; i += 256) sW1[i] = f2bu(W1[i]);
    for (int i = tid; i < 4096; i += 256) sW2[i] = f2bu(W2[i]);
    if (tid < 64) { sb1[tid] = b1[tid]; sb2[tid] = b2[tid]; }
    __syncthreads();
    size_t coff = (size_t)NN * 64;
    size_t noff = coff + (size_t)NN * 3;
    int lane = tid & 63;
    int wid = blockIdx.x * 4 + (tid >> 6);
    int nw = gridDim.x * 4;
    for (int n = wid; n < NN; n += nw) {
        float craw = g_cnt[n];
        float rinv = 1.f / fmaxf(craw, 1.f);
        float hl = h[(size_t)n * 64 + lane];
        float al = na[(size_t)n * 64 + lane];
        float obv = (craw > 0.f) ? ob[lane] : 0.f;
        float ml = g_msum[n * 64 + lane] * rinv + obv;
        float acc = sb1[lane];
        for (int i = 0; i < 64; i++) acc += __shfl(hl, i) * us2f(sW1[i * 64 + lane]);
        for (int i = 0; i < 64; i++) acc += __shfl(al, i) * us2f(sW1[(64 + i) * 64 + lane]);
        for (int i = 0; i < 64; i++) acc += __shfl(ml, i) * us2f(sW1[(128 + i) * 64 + lane]);
        float t = siluf(acc);
        float a2 = sb2[lane];
        for (int i = 0; i < 64; i++) a2 += __shfl(t, i) * us2f(sW2[i * 64 + lane]);
        out[(size_t)n * 64 + lane] = 0.2f * hl + 0.8f * a2;
        if (lane < 3) {
            out[coff + n * 3 + lane] = 0.2f * icoord[n * 3 + lane] + 0.8f * coord[n * 3 + lane]
                                       + g_xsum[n * 3 + lane] * rinv;
        }
        float nl = (lane < 3)
            ? (0.2f * invecs[n * 3 + lane] + 0.8f * nvecs[n * 3 + lane] + g_nsum[n * 3 + lane] * rinv)
            : 0.f;
        float nn = sqrtf(waveSum(nl * nl)) + 1e-8f;
        if (lane < 3) out[noff + n * 3 + lane] = nl / nn;
    }
}

extern "C" void kernel_launch(void* const* d_in, const int* in_sizes, int n_in,
                              void* d_out, int out_size, void* d_ws, size_t ws_size,
                              hipStream_t stream)
{
    const int* edges = (const int*)d_in[43];
    const int* klist = (const int*)d_in[44];
    auto F = [&](int i) { return (const float*)d_in[i]; };

    k_prep<<<512, 256, 0, stream>>>(F(19), F(20));
    k_geom<<<1024, 256, 0, stream>>>(F(1), F(2), edges, F(11), F(12));
    k_chem1<<<3125, 256, 0, stream>>>(F(0), F(4), F(3), edges, F(7), F(8));
    k_megaA<<<3125, 256, 0, stream>>>(F(9), F(10), F(13), F(14), F(15), F(16),
                                      F(17), F(18), F(22), F(27), F(28), F(29), F(30));
    k_megaB<<<3125, 256, 0, stream>>>(F(13), F(14), F(31), F(32), F(33), F(34),
                                      F(35), F(36), F(37), F(38), edges, F(2));
    k_q<<<dim3(3125, 4), 256, 0, stream>>>();
    k_attn2<<<2048, 256, 0, stream>>>(klist);
    k_us<<<3125, 256, 0, stream>>>(F(21), F(23), F(24), F(25), edges);
    k_node<<<640, 256, 0, stream>>>(F(0), F(4), F(1), F(2), F(5), F(6), F(26),
                                    F(39), F(40), F(41), F(42), (float*)d_out);
}

// Round 10
// 948.768 us; speedup vs baseline: 16.8344x; 1.0510x over previous
//
#include <hip/hip_runtime.h>

typedef unsigned short u16;
typedef unsigned int u32;
typedef __attribute__((ext_vector_type(8))) short s16x8;
typedef __attribute__((ext_vector_type(4))) float f32x4;

#define NN 10000
#define EE 200000
#define ES ((size_t)EE * 64)

#define DEVI __device__ __forceinline__

DEVI float us2f(u16 u) {
    union { u32 i; float f; } v; v.i = ((u32)u) << 16; return v.f;
}
DEVI u16 f2bu(float f) {
    union { float f; u32 i; } v; v.f = f;
    u32 x = v.i;
    return (u16)((x + 0x7fffu + ((x >> 16) & 1u)) >> 16);
}
DEVI float siluf(float x) { return x / (1.f + __expf(-x)); }
DEVI float sigmf(float x) { return 1.f / (1.f + __expf(-x)); }
DEVI float waveSum(float v) {
#pragma unroll
    for (int o = 32; o; o >>= 1) v += __shfl_xor(v, o);
    return v;
}
DEVI float quadSum(float v) {
#pragma unroll
    for (int o = 1; o < 16; o <<= 1) v += __shfl_xor(v, o);
    return v;
}

// ---- module-owned scratch ----
__device__ u16 g_hb[(size_t)NN * 64];    // bf16 copies of node features
__device__ u16 g_nab[(size_t)NN * 64];
__device__ u16 g_eab[(size_t)EE * 16];
__device__ u16 g_t1[ES];          // chem layer1 out
__device__ u16 g_z16[ES];
__device__ u16 g_qp4[4][ES];      // per-head q-projected
__device__ u16 g_t4[4][ES];       // per-head aggregated z
__device__ u16 g_M[4 * 4096];     // Wq Wk^T per head, [hd][k][n]
__device__ float g_b4[(size_t)EE * 4];   // [e][hd]
__device__ float g_nr[EE];        // nprod
__device__ float g_rad[EE];       // radial
__device__ float g_cdl[EE * 3];
__device__ float g_msum[NN * 64];
__device__ float g_xsum[NN * 3];
__device__ float g_nsum[NN * 3];
__device__ float g_cnt[NN];

// ---------------- M precompute + accumulator zeroing + bf16 conversion ----------------
__global__ __launch_bounds__(256) void k_prep(
    const float* __restrict__ Wq, const float* __restrict__ Wk,
    const float* __restrict__ h, const float* __restrict__ na, const float* __restrict__ ea)
{
    int t = blockIdx.x * 256 + threadIdx.x;
    if (t < 16384) {
        int hd = t >> 12, rem = t & 4095, k = rem >> 6, n = rem & 63;
        const float* wq = Wq + (size_t)hd * 4096 + k * 64;
        const float* wk = Wk + (size_t)hd * 4096 + n * 64;
        float acc = 0.f;
        for (int d = 0; d < 64; d++) acc += wq[d] * wk[d];
        g_M[t] = f2bu(acc);
    }
    int nt = gridDim.x * 256;
    for (int i = t; i < NN * 64; i += nt) { g_hb[i] = f2bu(h[i]); g_nab[i] = f2bu(na[i]); g_msum[i] = 0.f; }
    for (size_t i = t; i < (size_t)EE * 16; i += nt) g_eab[i] = f2bu(ea[i]);
    for (int i = t; i < NN * 3; i += nt) { g_xsum[i] = 0.f; g_nsum[i] = 0.f; }
    for (int i = t; i < NN; i += nt) g_cnt[i] = 0.f;
}

// ---------------- geometry: thread-per-edge ----------------
__global__ __launch_bounds__(256) void k_geom(
    const float* __restrict__ coord, const float* __restrict__ nvecs,
    const int* __restrict__ edges)
{
    int e = blockIdx.x * 256 + threadIdx.x;
    if (e >= EE) return;
    int r = edges[e], c = edges[EE + e];
    float d0 = coord[r * 3 + 0] - coord[c * 3 + 0];
    float d1 = coord[r * 3 + 1] - coord[c * 3 + 1];
    float d2 = coord[r * 3 + 2] - coord[c * 3 + 2];
    float radial = d0 * d0 + d1 * d1 + d2 * d2;
    float np = nvecs[r * 3 + 0] * nvecs[c * 3 + 0]
             + nvecs[r * 3 + 1] * nvecs[c * 3 + 1]
             + nvecs[r * 3 + 2] * nvecs[c * 3 + 2];
    float rinv = 1.f / (sqrtf(radial) + 1e-8f);
    g_cdl[e * 3 + 0] = d0 * rinv;
    g_cdl[e * 3 + 1] = d1 * rinv;
    g_cdl[e * 3 + 2] = d2 * rinv;
    g_nr[e] = np;
    g_rad[e] = radial;
}

// ---------------- chem layer1: gathered-A GEMM (bf16 sources), K=288 ----------------
__global__ __launch_bounds__(256) void k_chem1(
    const int* __restrict__ edges, const float* __restrict__ W1, const float* __restrict__ b1)
{
    __shared__ u16 sBT[64 * 296];
    int tid = threadIdx.x;
    for (int i = tid; i < 64 * 296; i += 256) {
        int n = i / 296, k = i - n * 296;
        sBT[i] = (k < 272) ? f2bu(W1[k * 64 + n]) : (u16)0;
    }
    __syncthreads();
    int lane = tid & 63, q = lane >> 4, ln = lane & 15, w = tid >> 6;
    int m0 = blockIdx.x * 64 + w * 16;
    int e = m0 + ln;
    int r_ = edges[e], c_ = edges[EE + e];
    f32x4 acc[4];
#pragma unroll
    for (int t = 0; t < 4; t++) acc[t] = (f32x4){0.f, 0.f, 0.f, 0.f};
#pragma unroll
    for (int k0 = 0; k0 < 9; k0++) {
        int k = k0 * 32 + q * 8;
        const u16* p = nullptr;
        if (k < 64)       p = g_hb  + (size_t)r_ * 64 + k;
        else if (k < 128) p = g_hb  + (size_t)c_ * 64 + (k - 64);
        else if (k < 192) p = g_nab + (size_t)r_ * 64 + (k - 128);
        else if (k < 256) p = g_nab + (size_t)c_ * 64 + (k - 192);
        else if (k < 272) p = g_eab + (size_t)e * 16 + (k - 256);
        s16x8 af = p ? *(const s16x8*)p : (s16x8){0, 0, 0, 0, 0, 0, 0, 0};
#pragma unroll
        for (int t = 0; t < 4; t++) {
            s16x8 bf = *(const s16x8*)(&sBT[(t * 16 + ln) * 296 + k0 * 32 + q * 8]);
            acc[t] = __builtin_amdgcn_mfma_f32_16x16x32_bf16(af, bf, acc[t], 0, 0, 0);
        }
    }
#pragma unroll
    for (int t = 0; t < 4; t++) {
        float bv = b1[t * 16 + ln];
#pragma unroll
        for (int r = 0; r < 4; r++)
            g_t1[(size_t)(m0 + q * 4 + r) * 64 + t * 16 + ln] = f2bu(siluf(acc[t][r] + bv));
    }
}

// helper: stage a 64x64 f32 weight as bf16 [n][k] stride-72 tile
DEVI void stageW(u16* dst, const float* src, int tid) {
    for (int i = tid; i < 4096; i += 256) {
        int k = i >> 6, n = i & 63;
        dst[n * 72 + k] = f2bu(src[i]);
    }
}

// ---------------- MegaAB: pos(inline p1), chem -> z, b4, phiu, phix, phin, scatter ----------------
__global__ __launch_bounds__(256) void k_megaAB(
    const float* __restrict__ chW2, const float* __restrict__ chb2,
    const float* __restrict__ pW1, const float* __restrict__ pb1,
    const float* __restrict__ posW2, const float* __restrict__ posb2,
    const float* __restrict__ shW, const float* __restrict__ shb,
    const float* __restrict__ attW, const float* __restrict__ attb,
    const float* __restrict__ Wb,
    const float* __restrict__ uW1, const float* __restrict__ ub1,
    const float* __restrict__ uW2, const float* __restrict__ ub2,
    const float* __restrict__ xW1, const float* __restrict__ xb1,
    const float* __restrict__ xW2, const float* __restrict__ xb2,
    const float* __restrict__ nW1, const float* __restrict__ nb1,
    const float* __restrict__ nW2, const float* __restrict__ nb2,
    const int* __restrict__ edges, const float* __restrict__ nvecs)
{
    __shared__ u16 sCH[64 * 72], sPW[64 * 72], sSH[64 * 72], sUW[64 * 72], sXW[64 * 72], sNW[64 * 72];
    __shared__ u16 T[4][16 * 72];
    __shared__ float sWB[256], sATT[64], sPW1[128], sPB1[64];
    int tid = threadIdx.x;
    stageW(sCH, chW2, tid); stageW(sPW, posW2, tid); stageW(sSH, shW, tid);
    stageW(sUW, uW1, tid);  stageW(sXW, xW1, tid);   stageW(sNW, nW1, tid);
    sWB[tid] = Wb[tid];
    if (tid < 128) sPW1[tid] = pW1[tid];
    if (tid < 64) { sATT[tid] = attW[tid]; sPB1[tid] = pb1[tid]; }
    __syncthreads();
    int lane = tid & 63, q = lane >> 4, ln = lane & 15, w = tid >> 6;
    int m0 = blockIdx.x * 64 + w * 16;
    // inline p1 A-fragment from nprod/radial (identical rounding to old g_p1 path)
    float np_ = g_nr[m0 + ln], rad_ = g_rad[m0 + ln];
    s16x8 p1f0, p1f1;
#pragma unroll
    for (int j = 0; j < 8; j++) {
        int k = q * 8 + j;
        p1f0[j] = (short)f2bu(siluf(sPB1[k] + np_ * sPW1[k] + rad_ * sPW1[64 + k]));
        k += 32;
        p1f1[j] = (short)f2bu(siluf(sPB1[k] + np_ * sPW1[k] + rad_ * sPW1[64 + k]));
    }
    // pos = silu(p1 @ posW2 + posb2)
    f32x4 pacc[4];
#pragma unroll
    for (int t = 0; t < 4; t++) {
        f32x4 a = (f32x4){0,0,0,0};
        a = __builtin_amdgcn_mfma_f32_16x16x32_bf16(p1f0, *(const s16x8*)(&sPW[(t * 16 + ln) * 72 + q * 8]), a, 0, 0, 0);
        a = __builtin_amdgcn_mfma_f32_16x16x32_bf16(p1f1, *(const s16x8*)(&sPW[(t * 16 + ln) * 72 + 32 + q * 8]), a, 0, 0, 0);
        pacc[t] = a;
    }
    float posD[4][4];
#pragma unroll
    for (int t = 0; t < 4; t++) {
        float pb = posb2[t * 16 + ln];
#pragma unroll
        for (int r = 0; r < 4; r++) posD[t][r] = siluf(pacc[t][r] + pb);
    }
    // chem = silu(t1 @ chW2 + chb2) -> transpose via T
    f32x4 cacc[4];
#pragma unroll
    for (int t = 0; t < 4; t++) cacc[t] = (f32x4){0,0,0,0};
    {
        const u16* ar = g_t1 + (size_t)(m0 + ln) * 64;
#pragma unroll
        for (int k0 = 0; k0 < 2; k0++) {
            s16x8 af = *(const s16x8*)(ar + k0 * 32 + q * 8);
#pragma unroll
            for (int t = 0; t < 4; t++) {
                s16x8 bf = *(const s16x8*)(&sCH[(t * 16 + ln) * 72 + k0 * 32 + q * 8]);
                cacc[t] = __builtin_amdgcn_mfma_f32_16x16x32_bf16(af, bf, cacc[t], 0, 0, 0);
            }
        }
    }
#pragma unroll
    for (int t = 0; t < 4; t++) {
        float cb = chb2[t * 16 + ln];
#pragma unroll
        for (int r = 0; r < 4; r++)
            T[w][(q * 4 + r) * 72 + t * 16 + ln] = f2bu(siluf(cacc[t][r] + cb));
    }
    asm volatile("s_waitcnt lgkmcnt(0)" ::: "memory");
    s16x8 ca0 = *(const s16x8*)(&T[w][ln * 72 + q * 8]);
    s16x8 ca1 = *(const s16x8*)(&T[w][ln * 72 + 32 + q * 8]);
    // out = silu(chem @ shW + shb) * pos ; att -> z ; b4
    f32x4 sacc[4];
#pragma unroll
    for (int t = 0; t < 4; t++) {
        f32x4 a = (f32x4){0,0,0,0};
        a = __builtin_amdgcn_mfma_f32_16x16x32_bf16(ca0, *(const s16x8*)(&sSH[(t * 16 + ln) * 72 + q * 8]), a, 0, 0, 0);
        a = __builtin_amdgcn_mfma_f32_16x16x32_bf16(ca1, *(const s16x8*)(&sSH[(t * 16 + ln) * 72 + 32 + q * 8]), a, 0, 0, 0);
        sacc[t] = a;
    }
    float zv[4][4];
    float part[4] = {0.f, 0.f, 0.f, 0.f};
#pragma unroll
    for (int t = 0; t < 4; t++) {
        float sb = shb[t * 16 + ln];
        float aw = sATT[t * 16 + ln];
#pragma unroll
        for (int r = 0; r < 4; r++) {
            float o = siluf(sacc[t][r] + sb) * posD[t][r];
            zv[t][r] = o;
            part[r] += o * aw;
        }
    }
    float ab = attb[0];
#pragma unroll
    for (int r = 0; r < 4; r++) {
        float sg = sigmf(quadSum(part[r]) + ab);
        size_t row = m0 + q * 4 + r;
#pragma unroll
        for (int t = 0; t < 4; t++) {
            float z = zv[t][r] * sg;
            zv[t][r] = z;
            g_z16[row * 64 + t * 16 + ln] = f2bu(z);
        }
    }
#pragma unroll
    for (int hd = 0; hd < 4; hd++) {
#pragma unroll
        for (int r = 0; r < 4; r++) {
            float p = 0.f;
#pragma unroll
            for (int t = 0; t < 4; t++) p += zv[t][r] * sWB[hd * 64 + t * 16 + ln];
            p = quadSum(p);
            if (ln == hd) g_b4[(size_t)(m0 + q * 4 + r) * 4 + hd] = p;
        }
    }
    // phiu = silu(chem @ uW1 + ub1) . uW2 + ub2   (kept in registers)
    f32x4 uacc[4];
#pragma unroll
    for (int t = 0; t < 4; t++) {
        f32x4 a = (f32x4){0,0,0,0};
        a = __builtin_amdgcn_mfma_f32_16x16x32_bf16(ca0, *(const s16x8*)(&sUW[(t * 16 + ln) * 72 + q * 8]), a, 0, 0, 0);
        a = __builtin_amdgcn_mfma_f32_16x16x32_bf16(ca1, *(const s16x8*)(&sUW[(t * 16 + ln) * 72 + 32 + q * 8]), a, 0, 0, 0);
        uacc[t] = a;
    }
    float up[4] = {0.f, 0.f, 0.f, 0.f};
#pragma unroll
    for (int t = 0; t < 4; t++) {
        float ub = ub1[t * 16 + ln];
        float w2 = uW2[t * 16 + ln];
#pragma unroll
        for (int r = 0; r < 4; r++) up[r] += siluf(uacc[t][r] + ub) * w2;
    }
    float ub2v = ub2[0];
    float pu[4];
#pragma unroll
    for (int r = 0; r < 4; r++) pu[r] = quadSum(up[r]) + ub2v;
    // pos transpose (reuse T[w]) -> phix/phin GEMMs
#pragma unroll
    for (int t = 0; t < 4; t++)
#pragma unroll
        for (int r = 0; r < 4; r++)
            T[w][(q * 4 + r) * 72 + t * 16 + ln] = f2bu(posD[t][r]);
    asm volatile("s_waitcnt lgkmcnt(0)" ::: "memory");
    s16x8 pa0 = *(const s16x8*)(&T[w][ln * 72 + q * 8]);
    s16x8 pa1 = *(const s16x8*)(&T[w][ln * 72 + 32 + q * 8]);
    f32x4 xacc[4], nacc[4];
#pragma unroll
    for (int t = 0; t < 4; t++) {
        f32x4 a = (f32x4){0,0,0,0}, b = (f32x4){0,0,0,0};
        a = __builtin_amdgcn_mfma_f32_16x16x32_bf16(pa0, *(const s16x8*)(&sXW[(t * 16 + ln) * 72 + q * 8]), a, 0, 0, 0);
        a = __builtin_amdgcn_mfma_f32_16x16x32_bf16(pa1, *(const s16x8*)(&sXW[(t * 16 + ln) * 72 + 32 + q * 8]), a, 0, 0, 0);
        b = __builtin_amdgcn_mfma_f32_16x16x32_bf16(pa0, *(const s16x8*)(&sNW[(t * 16 + ln) * 72 + q * 8]), b, 0, 0, 0);
        b = __builtin_amdgcn_mfma_f32_16x16x32_bf16(pa1, *(const s16x8*)(&sNW[(t * 16 + ln) * 72 + 32 + q * 8]), b, 0, 0, 0);
        xacc[t] = a; nacc[t] = b;
    }
    float xp[4] = {0,0,0,0}, npv[4] = {0,0,0,0};
#pragma unroll
    for (int t = 0; t < 4; t++) {
        float xb = xb1[t * 16 + ln], nb = nb1[t * 16 + ln];
        float xw = xW2[t * 16 + ln], nw = nW2[t * 16 + ln];
#pragma unroll
        for (int r = 0; r < 4; r++) {
            xp[r] += siluf(xacc[t][r] + xb) * xw;
            npv[r] += siluf(nacc[t][r] + nb) * nw;
        }
    }
    float xb2v = xb2[0], nb2v = nb2[0];
#pragma unroll
    for (int r = 0; r < 4; r++) {
        float phix = quadSum(xp[r]) + xb2v;
        float phin = quadSum(npv[r]) + nb2v;
        int row = m0 + q * 4 + r;
        float tx = pu[r] * phix, tn = pu[r] * phin;
        int rr = edges[row], cc = edges[EE + row];
        if (ln < 3) {
            atomicAdd(&g_xsum[rr * 3 + ln], g_cdl[row * 3 + ln] * tx);
            atomicAdd(&g_nsum[rr * 3 + ln], nvecs[cc * 3 + ln] * tn);
        }
        if (ln == 3) atomicAdd(&g_cnt[rr], 1.f);
    }
}

// ---------------- qp: all 4 heads in one pass (z read once) ----------------
__global__ __launch_bounds__(256) void k_q4()
{
    __shared__ u16 sM[4][64 * 72];
    int tid = threadIdx.x;
    for (int i = tid; i < 16384; i += 256) {
        int hd = i >> 12, rem = i & 4095, k = rem >> 6, n = rem & 63;
        sM[hd][n * 72 + k] = g_M[i];
    }
    __syncthreads();
    int lane = tid & 63, q = lane >> 4, ln = lane & 15, w = tid >> 6;
    int m0 = blockIdx.x * 64 + w * 16;
    const u16* ar = g_z16 + (size_t)(m0 + ln) * 64;
    s16x8 af0 = *(const s16x8*)(ar + q * 8);
    s16x8 af1 = *(const s16x8*)(ar + 32 + q * 8);
    for (int hd = 0; hd < 4; hd++) {
        f32x4 aM[4];
#pragma unroll
        for (int t = 0; t < 4; t++) {
            f32x4 a = (f32x4){0,0,0,0};
            a = __builtin_amdgcn_mfma_f32_16x16x32_bf16(af0, *(const s16x8*)(&sM[hd][(t * 16 + ln) * 72 + q * 8]), a, 0, 0, 0);
            a = __builtin_amdgcn_mfma_f32_16x16x32_bf16(af1, *(const s16x8*)(&sM[hd][(t * 16 + ln) * 72 + 32 + q * 8]), a, 0, 0, 0);
            aM[t] = a;
        }
#pragma unroll
        for (int t = 0; t < 4; t++)
#pragma unroll
            for (int r = 0; r < 4; r++)
                g_qp4[hd][(size_t)(m0 + q * 4 + r) * 64 + t * 16 + ln] = f2bu(aM[t][r]);
    }
}

// ---------------- attention: MFMA scores, LDS-fed PV (single z gather) ----------------
__global__ __launch_bounds__(256) void k_attn2(const int* __restrict__ klist)
{
    __shared__ __align__(16) float sA[4][4][16];   // [wave][hd][j]
    __shared__ u16 zT[4][16 * 72];                 // [wave][j][d]
    int tid = threadIdx.x;
    int w = tid >> 6, lane = tid & 63, q = lane >> 4, ln = lane & 15;
    int wid = blockIdx.x * 4 + w;
    int nw = gridDim.x * 4;
    u16* zw = zT[w];
    for (int e = wid; e < EE; e += nw) {
        int kv = (lane < 32) ? klist[(size_t)e * 32 + lane] : -1;
        int ij_ln = __shfl(kv, ln);
        s16x8 za0 = {0,0,0,0,0,0,0,0}, za1 = {0,0,0,0,0,0,0,0};
        if (ij_ln >= 0) {
            const u16* zr = g_z16 + (size_t)ij_ln * 64;
            za0 = *(const s16x8*)(zr + q * 8);
            za1 = *(const s16x8*)(zr + 32 + q * 8);
        }
        s16x8 qb0 = {0,0,0,0,0,0,0,0}, qb1 = {0,0,0,0,0,0,0,0};
        if (ln < 4) {
            const u16* qr = &g_qp4[ln][(size_t)e * 64];
            qb0 = *(const s16x8*)(qr + q * 8);
            qb1 = *(const s16x8*)(qr + 32 + q * 8);
        }
        f32x4 sc = (f32x4){0.f, 0.f, 0.f, 0.f};
        sc = __builtin_amdgcn_mfma_f32_16x16x32_bf16(za0, qb0, sc, 0, 0, 0);
        sc = __builtin_amdgcn_mfma_f32_16x16x32_bf16(za1, qb1, sc, 0, 0, 0);
        *(s16x8*)(&zw[ln * 72 + q * 8]) = za0;
        *(s16x8*)(&zw[ln * 72 + 32 + q * 8]) = za1;
        float s[4];
#pragma unroll
        for (int r = 0; r < 4; r++) {
            int j = q * 4 + r;
            int ij = __shfl(kv, j);
            int jj = __shfl(kv, 16 + j);
            float bvl = (ij >= 0 && ln < 4) ? g_b4[(size_t)jj * 4 + ln] : 0.f;
            s[r] = (ij >= 0) ? (0.125f * sc[r] + bvl) : 0.f;
        }
        float mx = fmaxf(fmaxf(s[0], s[1]), fmaxf(s[2], s[3]));
        mx = fmaxf(mx, __shfl_xor(mx, 16));
        mx = fmaxf(mx, __shfl_xor(mx, 32));
        float ex[4], ps = 0.f;
#pragma unroll
        for (int r = 0; r < 4; r++) { ex[r] = __expf(s[r] - mx); ps += ex[r]; }
        ps += __shfl_xor(ps, 16);
        ps += __shfl_xor(ps, 32);
        float inv = 1.f / ps;
        if (ln < 4)
            *(f32x4*)&sA[w][ln][q * 4] = (f32x4){ex[0] * inv, ex[1] * inv, ex[2] * inv, ex[3] * inv};
        asm volatile("s_waitcnt lgkmcnt(0)" ::: "memory");
        float t0 = 0.f, t1 = 0.f, t2 = 0.f, t3 = 0.f;
#pragma unroll
        for (int j4 = 0; j4 < 4; j4++) {
            f32x4 a0 = *(const f32x4*)&sA[w][0][j4 * 4];
            f32x4 a1 = *(const f32x4*)&sA[w][1][j4 * 4];
            f32x4 a2 = *(const f32x4*)&sA[w][2][j4 * 4];
            f32x4 a3 = *(const f32x4*)&sA[w][3][j4 * 4];
#pragma unroll
            for (int r = 0; r < 4; r++) {
                float zz = us2f(zw[(j4 * 4 + r) * 72 + lane]);
                t0 += a0[r] * zz; t1 += a1[r] * zz; t2 += a2[r] * zz; t3 += a3[r] * zz;
            }
        }
        size_t ob = (size_t)e * 64 + lane;
        g_t4[0][ob] = f2bu(t0);
        g_t4[1][ob] = f2bu(t1);
        g_t4[2][ob] = f2bu(t2);
        g_t4[3][ob] = f2bu(t3);
    }
}

// ---------------- fused heads: u=(t@Wv)*sigm(z@Wg+bg); m=Σ_hd u@oW_hd; one atomic pass ----------------
__global__ __launch_bounds__(256) void k_us(
    const float* __restrict__ Wv, const float* __restrict__ Wg, const float* __restrict__ bg,
    const float* __restrict__ oW, const int* __restrict__ edges)
{
    __shared__ u16 sV[64 * 72], sO[64 * 72], sG[64 * 72];
    __shared__ u16 sU[4][16 * 72];
    int tid = threadIdx.x;
    int lane = tid & 63, q = lane >> 4, ln = lane & 15, w = tid >> 6;
    int m0 = blockIdx.x * 64 + w * 16;
    const u16* zr = g_z16 + (size_t)(m0 + ln) * 64;
    s16x8 za[2];
    za[0] = *(const s16x8*)(zr + q * 8);
    za[1] = *(const s16x8*)(zr + 32 + q * 8);
    f32x4 macc[4];
#pragma unroll
    for (int t = 0; t < 4; t++) macc[t] = (f32x4){0,0,0,0};
    for (int hd = 0; hd < 4; hd++) {
        if (hd) __syncthreads();
        stageW(sV, Wv + (size_t)hd * 4096, tid);
        stageW(sO, oW + (size_t)hd * 4096, tid);
        stageW(sG, Wg + (size_t)hd * 4096, tid);
        __syncthreads();
        f32x4 vacc[4], gacc[4];
#pragma unroll
        for (int t = 0; t < 4; t++) { vacc[t] = (f32x4){0,0,0,0}; gacc[t] = (f32x4){0,0,0,0}; }
        const u16* ar = &g_t4[hd][(size_t)(m0 + ln) * 64];
#pragma unroll
        for (int k0 = 0; k0 < 2; k0++) {
            s16x8 af = *(const s16x8*)(ar + k0 * 32 + q * 8);
#pragma unroll
            for (int t = 0; t < 4; t++) {
                vacc[t] = __builtin_amdgcn_mfma_f32_16x16x32_bf16(
                    af, *(const s16x8*)(&sV[(t * 16 + ln) * 72 + k0 * 32 + q * 8]), vacc[t], 0, 0, 0);
                gacc[t] = __builtin_amdgcn_mfma_f32_16x16x32_bf16(
                    za[k0], *(const s16x8*)(&sG[(t * 16 + ln) * 72 + k0 * 32 + q * 8]), gacc[t], 0, 0, 0);
            }
        }
#pragma unroll
        for (int t = 0; t < 4; t++) {
            float bb = bg[hd * 64 + t * 16 + ln];
#pragma unroll
            for (int r = 0; r < 4; r++) {
                float u = vacc[t][r] * sigmf(gacc[t][r] + bb);
                sU[w][(q * 4 + r) * 72 + t * 16 + ln] = f2bu(u);
            }
        }
        asm volatile("s_waitcnt lgkmcnt(0)" ::: "memory");
#pragma unroll
        for (int k0 = 0; k0 < 2; k0++) {
            s16x8 af = *(const s16x8*)(&sU[w][ln * 72 + k0 * 32 + q * 8]);
#pragma unroll
            for (int t = 0; t < 4; t++) {
                macc[t] = __builtin_amdgcn_mfma_f32_16x16x32_bf16(
                    af, *(const s16x8*)(&sO[(t * 16 + ln) * 72 + k0 * 32 + q * 8]), macc[t], 0, 0, 0);
            }
        }
    }
#pragma unroll
    for (int r = 0; r < 4; r++) {
        int dst = edges[m0 + q * 4 + r] * 64;
#pragma unroll
        for (int t = 0; t < 4; t++) atomicAdd(&g_msum[dst + t * 16 + ln], macc[t][r]);
    }
}

// ---------------- node finalize ----------------
__global__ __launch_bounds__(256) void k_node(
    const float* __restrict__ h, const float* __restrict__ na,
    const float* __restrict__ coord, const float* __restrict__ nvecs,
    const float* __restrict__ icoord, const float* __restrict__ invecs,
    const float* __restrict__ ob,
    const float* __restrict__ W1, const float* __restrict__ b1,
    const float* __restrict__ W2, const float* __restrict__ b2,
    float* __restrict__ out)
{
    __shared__ u16 sW1[192 * 64], sW2[4096];
    __shared__ float sb1[64], sb2[64];
    int tid = threadIdx.x;
    for (int i = tid; i < 192 * 64; i += 256) sW1[i] = f2bu(W1[i]);
    for (int i = tid; i < 4096; i += 256) sW2[i] = f2bu(W2[i]);
    if (tid < 64) { sb1[tid] = b1[tid]; sb2[tid] = b2[tid]; }
    __syncthreads();
    size_t coff = (size_t)NN * 64;
    size_t noff = coff + (size_t)NN * 3;
    int lane = tid & 63;
    int wid = blockIdx.x * 4 + (tid >> 6);
    int nw = gridDim.x * 4;
    for (int n = wid; n < NN; n += nw) {
        float craw = g_cnt[n];
        float rinv = 1.f / fmaxf(craw, 1.f);
        float hl = h[(size_t)n * 64 + lane];
        float al = na[(size_t)n * 64 + lane];
        float obv = (craw > 0.f) ? ob[lane] : 0.f;
        float ml = g_msum[n * 64 + lane] * rinv + obv;
        float acc = sb1[lane];
        for (int i = 0; i < 64; i++) acc += __shfl(hl, i) * us2f(sW1[i * 64 + lane]);
        for (int i = 0; i < 64; i++) acc += __shfl(al, i) * us2f(sW1[(64 + i) * 64 + lane]);
        for (int i = 0; i < 64; i++) acc += __shfl(ml, i) * us2f(sW1[(128 + i) * 64 + lane]);
        float t = siluf(acc);
        float a2 = sb2[lane];
        for (int i = 0; i < 64; i++) a2 += __shfl(t, i) * us2f(sW2[i * 64 + lane]);
        out[(size_t)n * 64 + lane] = 0.2f * hl + 0.8f * a2;
        if (lane < 3) {
            out[coff + n * 3 + lane] = 0.2f * icoord[n * 3 + lane] + 0.8f * coord[n * 3 + lane]
                                       + g_xsum[n * 3 + lane] * rinv;
        }
        float nl = (lane < 3)
            ? (0.2f * invecs[n * 3 + lane] + 0.8f * nvecs[n * 3 + lane] + g_nsum[n * 3 + lane] * rinv)
            : 0.f;
        float nn = sqrtf(waveSum(nl * nl)) + 1e-8f;
        if (lane < 3) out[noff + n * 3 + lane] = nl / nn;
    }
}

extern "C" void kernel_launch(void* const* d_in, const int* in_sizes, int n_in,
                              void* d_out, int out_size, void* d_ws, size_t ws_size,
                              hipStream_t stream)
{
    const int* edges = (const int*)d_in[43];
    const int* klist = (const int*)d_in[44];
    auto F = [&](int i) { return (const float*)d_in[i]; };

    k_prep<<<512, 256, 0, stream>>>(F(19), F(20), F(0), F(4), F(3));
    k_geom<<<782, 256, 0, stream>>>(F(1), F(2), edges);
    k_chem1<<<3125, 256, 0, stream>>>(edges, F(7), F(8));
    k_megaAB<<<3125, 256, 0, stream>>>(F(9), F(10), F(11), F(12), F(13), F(14),
                                       F(15), F(16), F(17), F(18), F(22),
                                       F(27), F(28), F(29), F(30),
                                       F(31), F(32), F(33), F(34),
                                       F(35), F(36), F(37), F(38),
                                       edges, F(2));
    k_q4<<<3125, 256, 0, stream>>>();
    k_attn2<<<2048, 256, 0, stream>>>(klist);
    k_us<<<3125, 256, 0, stream>>>(F(21), F(23), F(24), F(25), edges);
    k_node<<<640, 256, 0, stream>>>(F(0), F(4), F(1), F(2), F(5), F(6), F(26),
                                    F(39), F(40), F(41), F(42), (float*)d_out);
}